// Round 7
// baseline (654.838 us; speedup 1.0000x reference)
//
#include <hip/hip_runtime.h>
#include <hip/hip_bf16.h>

// HGNNP_GCN + ClusterNet forward, MI355X (round 7).
// R6 counters: k_gcn_gather<128> 95us, FETCH 197MB vs 25.6MB source buffer ->
// random gather defeats per-XCD L2 (no index locality), L2-miss-traffic-bound.
// This round: all gather operands staged as bf16 (GEMM outputs + e_feat),
// halving gather-side L2-miss bytes. Accumulation stays f32.

#define NN   50000   // nodes
#define EE   800000  // directed edges
#define NINC 200000  // incidence entries
#define NEH  10000   // hyperedges
#define KCL  10      // clusters

// output element offsets (flat concat: mu | r | embeds | dist)
#define MU_OFF  0
#define R_OFF   640
#define EMB_OFF 500640
#define D_OFF   3700640

typedef __hip_bfloat16 bf16;
typedef unsigned short u16;

__device__ __forceinline__ float b2f(bf16 v){ return __bfloat162float(v); }
__device__ __forceinline__ float us2f(u16 u){ return __uint_as_float(((unsigned)u) << 16); }
__device__ __forceinline__ u16 f2bu(float f){
  unsigned u = __float_as_uint(f);
  return (u16)((u + 0x7fffu + ((u >> 16) & 1u)) >> 16);   // RNE
}
__device__ __forceinline__ bf16 f2b(float f){
  u16 r = f2bu(f);
  bf16 h;
  reinterpret_cast<u16&>(h) = r;
  return h;
}
// external-float load/store, dtype chosen by uniform runtime flag
__device__ __forceinline__ float ldf(const void* p, size_t i, int isbf){
  return isbf ? b2f(((const bf16*)p)[i]) : ((const float*)p)[i];
}
__device__ __forceinline__ void stf(void* p, size_t i, float v, int isbf){
  if (isbf) ((bf16*)p)[i] = f2b(v);
  else      ((float*)p)[i] = v;
}

// ---------------- dtype detector ----------------
__global__ void k_detect(const u16* __restrict__ xr, int* flag){
  __shared__ int bad;
  if (threadIdx.x == 0) bad = 0;
  __syncthreads();
  for (int i = threadIdx.x; i < 4096; i += 256){
    int e = (xr[i] >> 7) & 0xFF;
    if (e >= 0xEF) bad = 1;     // f32 low-halves have random exponents
  }
  __syncthreads();
  if (threadIdx.x == 0) *flag = bad ? 0 : 1;   // 1 = bf16, 0 = f32
}

// ---------------- CSR build: count / scan / fill ----------------
__global__ void k_cnt(const int* __restrict__ dst, const int* __restrict__ hv,
                      const int* __restrict__ he, int* cg, int* cv, int* ce){
  int i = blockIdx.x*256 + threadIdx.x;
  if (i < EE)   atomicAdd(&cg[dst[i]], 1);
  if (i < NINC){ atomicAdd(&cv[hv[i]], 1); atomicAdd(&ce[he[i]], 1); }
}

__global__ void k_invs(const int* __restrict__ cg, const int* __restrict__ cv,
                       const int* __restrict__ ce,
                       float* dinv, float* invd, float* invv, float* inve){
  int i = blockIdx.x*256 + threadIdx.x;
  if (i < NN){
    float d = 1.0f + (float)cg[i];     // self-loop included
    dinv[i] = rsqrtf(d);
    invd[i] = 1.0f / d;
    invv[i] = 1.0f / fmaxf((float)cv[i], 1.0f);
  }
  if (i < NEH) inve[i] = 1.0f / fmaxf((float)ce[i], 1.0f);
}

// exclusive scan, 256 elems/block (Hillis-Steele in LDS)
__global__ void k_scan1(const int* __restrict__ in, int* __restrict__ out,
                        int* __restrict__ bsum, int n){
  __shared__ int s[256];
  int t = threadIdx.x, i = blockIdx.x*256 + t;
  int v = (i < n) ? in[i] : 0;
  s[t] = v; __syncthreads();
  #pragma unroll
  for (int off = 1; off < 256; off <<= 1){
    int add = (t >= off) ? s[t-off] : 0;
    __syncthreads();
    s[t] += add;
    __syncthreads();
  }
  if (i < n) out[i] = s[t] - v;        // exclusive
  if (t == 255) bsum[blockIdx.x] = s[255];
}

__global__ void k_scan2(int* bsum, int nb){   // single block, nb <= 256
  __shared__ int s[256];
  int t = threadIdx.x;
  int v = (t < nb) ? bsum[t] : 0;
  s[t] = v; __syncthreads();
  #pragma unroll
  for (int off = 1; off < 256; off <<= 1){
    int add = (t >= off) ? s[t-off] : 0;
    __syncthreads();
    s[t] += add;
    __syncthreads();
  }
  if (t < nb) bsum[t] = s[t] - v;
}

__global__ void k_scan3(int* __restrict__ rp, int* __restrict__ cur,
                        const int* __restrict__ bsum, int n){
  int i = blockIdx.x*256 + threadIdx.x;
  if (i < n){ int v = rp[i] + bsum[blockIdx.x]; rp[i] = v; cur[i] = v; }
}

__global__ void k_fill_gcn(const int* __restrict__ src, const int* __restrict__ dst,
                           int* cur, int* __restrict__ csr){
  int i = blockIdx.x*256 + threadIdx.x;
  if (i < EE){ int p = atomicAdd(&cur[dst[i]], 1); csr[p] = src[i]; }
}

__global__ void k_fill_hg(const int* __restrict__ hv, const int* __restrict__ he,
                          int* cur_e, int* __restrict__ csr_e,
                          int* cur_v, int* __restrict__ csr_v){
  int i = blockIdx.x*256 + threadIdx.x;
  if (i < NINC){
    int v = hv[i], e = he[i];
    csr_e[atomicAdd(&cur_e[e], 1)] = v;
    csr_v[atomicAdd(&cur_v[v], 1)] = e;
  }
}

// ---------------- GEMM v2: C[M][NCOL] = A[M][KDIM] @ W[KDIM][NCOL] ----------------
// OUTBF: store C as bf16 (consumed only by gathers).
template<int KDIM, int NCOL, bool AEXT, bool OUTBF>
__global__ __launch_bounds__(256) void k_gemmv2(const void* __restrict__ Av,
    const void* __restrict__ W, const void* __restrict__ bias,
    void* __restrict__ C, int M, int relu, const int* __restrict__ flag)
{
  constexpr int BM = 64, KC = 32;
  constexpr int CG  = NCOL/4;      // col groups (float4)
  constexpr int RS  = 256/CG;      // row slots
  constexpr int RPT = BM/RS;       // rows per thread (128->8, 64->4)
  __shared__ __align__(16) float Ws[KC][NCOL];
  __shared__ __align__(16) float As[BM][KC+4];
  const int isbf = flag[0];
  const int tid = threadIdx.x;
  const int cg = tid % CG, rs = tid / CG;
  const int row0 = blockIdx.x * BM;

  float acc[RPT][4];
  #pragma unroll
  for (int r=0;r<RPT;r++){ acc[r][0]=acc[r][1]=acc[r][2]=acc[r][3]=0.f; }

  float4* Ws4 = (float4*)&Ws[0][0];
  const float* Af = (const float*)Av;
  const bf16*  Ab = (const bf16*)Av;

  for (int kk = 0; kk < KDIM; kk += KC){
    #pragma unroll
    for (int s = tid; s < KC*NCOL/4; s += 256){
      if (isbf){
        const bf16* wp = (const bf16*)W + (size_t)kk*NCOL + s*4;
        Ws4[s] = make_float4(b2f(wp[0]), b2f(wp[1]), b2f(wp[2]), b2f(wp[3]));
      } else {
        Ws4[s] = ((const float4*)((const float*)W + (size_t)kk*NCOL))[s];
      }
    }
    #pragma unroll
    for (int s = tid; s < BM*KC/4; s += 256){
      int r = s / (KC/4), kq = s % (KC/4);
      int grow = row0 + r;
      float4 v = make_float4(0.f,0.f,0.f,0.f);
      if (grow < M){
        size_t off = (size_t)grow*KDIM + kk + kq*4;
        if (AEXT && isbf){
          const bf16* ap = Ab + off;
          v = make_float4(b2f(ap[0]), b2f(ap[1]), b2f(ap[2]), b2f(ap[3]));
        } else {
          v = *(const float4*)(Af + off);
        }
      }
      *(float4*)&As[r][kq*4] = v;
    }
    __syncthreads();

    #pragma unroll
    for (int k4 = 0; k4 < KC/4; ++k4){
      float4 w0 = *(const float4*)&Ws[k4*4+0][cg*4];
      float4 w1 = *(const float4*)&Ws[k4*4+1][cg*4];
      float4 w2 = *(const float4*)&Ws[k4*4+2][cg*4];
      float4 w3 = *(const float4*)&Ws[k4*4+3][cg*4];
      #pragma unroll
      for (int rr = 0; rr < RPT; ++rr){
        float4 a = *(const float4*)&As[rs + rr*RS][k4*4];
        acc[rr][0] = fmaf(a.x, w0.x, acc[rr][0]);
        acc[rr][1] = fmaf(a.x, w0.y, acc[rr][1]);
        acc[rr][2] = fmaf(a.x, w0.z, acc[rr][2]);
        acc[rr][3] = fmaf(a.x, w0.w, acc[rr][3]);
        acc[rr][0] = fmaf(a.y, w1.x, acc[rr][0]);
        acc[rr][1] = fmaf(a.y, w1.y, acc[rr][1]);
        acc[rr][2] = fmaf(a.y, w1.z, acc[rr][2]);
        acc[rr][3] = fmaf(a.y, w1.w, acc[rr][3]);
        acc[rr][0] = fmaf(a.z, w2.x, acc[rr][0]);
        acc[rr][1] = fmaf(a.z, w2.y, acc[rr][1]);
        acc[rr][2] = fmaf(a.z, w2.z, acc[rr][2]);
        acc[rr][3] = fmaf(a.z, w2.w, acc[rr][3]);
        acc[rr][0] = fmaf(a.w, w3.x, acc[rr][0]);
        acc[rr][1] = fmaf(a.w, w3.y, acc[rr][1]);
        acc[rr][2] = fmaf(a.w, w3.z, acc[rr][2]);
        acc[rr][3] = fmaf(a.w, w3.w, acc[rr][3]);
      }
    }
    __syncthreads();
  }

  float4 bv = make_float4(0.f,0.f,0.f,0.f);
  if (bias){
    bv.x = ldf(bias, cg*4+0, isbf); bv.y = ldf(bias, cg*4+1, isbf);
    bv.z = ldf(bias, cg*4+2, isbf); bv.w = ldf(bias, cg*4+3, isbf);
  }
  #pragma unroll
  for (int rr = 0; rr < RPT; ++rr){
    int row = row0 + rs + rr*RS;
    if (row < M){
      float o0=acc[rr][0]+bv.x, o1=acc[rr][1]+bv.y;
      float o2=acc[rr][2]+bv.z, o3=acc[rr][3]+bv.w;
      if (relu){ o0=fmaxf(o0,0.f); o1=fmaxf(o1,0.f); o2=fmaxf(o2,0.f); o3=fmaxf(o3,0.f); }
      if (OUTBF){
        ushort4 pk = make_ushort4(f2bu(o0), f2bu(o1), f2bu(o2), f2bu(o3));
        *(ushort4*)((u16*)C + (size_t)row*NCOL + cg*4) = pk;
      } else {
        *(float4*)((float*)C + (size_t)row*NCOL + cg*4) = make_float4(o0,o1,o2,o3);
      }
    }
  }
}

// ---------------- fused GCN gather (bf16 operand): selfloop+edges+bias+relu ----------------
template<int F>
__global__ void k_gcn_gather(const int* __restrict__ rp, const int* __restrict__ cnt,
    const int* __restrict__ csr, const float* __restrict__ dinv,
    const float* __restrict__ invd, const u16* __restrict__ h,
    const void* __restrict__ bias, float* __restrict__ out,
    int relu, const int* __restrict__ flag)
{
  int d = blockIdx.x, j = threadIdx.x;
  float acc = us2f(h[(size_t)d*F + j]) * invd[d];   // self-loop term
  const float dd = dinv[d];
  int k = rp[d], e = k + cnt[d];
  for (; k < e; ++k){
    int s = csr[k];                                 // broadcast across block
    acc = fmaf(us2f(h[(size_t)s*F + j]), dinv[s]*dd, acc);
  }
  acc += ldf(bias, j, flag[0]);
  if (relu) acc = fmaxf(acc, 0.f);
  out[(size_t)d*F + j] = acc;
}

// ---------------- fused hypergraph gathers (mean, bf16 operands) ----------------
template<int F>
__global__ void k_hg_e_gather(const int* __restrict__ rp, const int* __restrict__ cnt,
    const int* __restrict__ csr, const float* __restrict__ inve,
    const u16* __restrict__ h, u16* __restrict__ ef)
{
  int e = blockIdx.x, j = threadIdx.x;
  int k = rp[e], n = cnt[e];
  float acc = 0.f;
  for (int t = 0; t < n; ++t)
    acc += us2f(h[(size_t)csr[k+t]*F + j]);
  ef[(size_t)e*F + j] = f2bu(acc * inve[e]);
}

template<int F>
__global__ void k_hg_v_gather(const int* __restrict__ rp, const int* __restrict__ cnt,
    const int* __restrict__ csr, const float* __restrict__ invv,
    const u16* __restrict__ ef, float* __restrict__ out, int relu)
{
  int v = blockIdx.x, j = threadIdx.x;
  int k = rp[v], n = cnt[v];
  float acc = 0.f;
  for (int t = 0; t < n; ++t)
    acc += us2f(ef[(size_t)csr[k+t]*F + j]);
  acc *= invv[v];
  if (relu) acc = fmaxf(acc, 0.f);
  out[(size_t)v*F + j] = acc;
}

// ---------------- embeds + row normalize ----------------
__global__ void k_embeds(const float* __restrict__ x2, const float* __restrict__ x4,
                         void* __restrict__ out, float* __restrict__ data,
                         const int* __restrict__ flag){
  int row  = blockIdx.x*4 + (threadIdx.x >> 6);
  int lane = threadIdx.x & 63;
  if (row >= NN) return;
  size_t idx = (size_t)row*64 + lane;
  float v = 0.5f*(x2[idx] + x4[idx]);
  float ss = v*v;
  #pragma unroll
  for (int off=32; off>0; off>>=1) ss += __shfl_xor(ss, off);
  float inv = rsqrtf(ss);
  data[idx] = v*inv;
  stf(out, EMB_OFF + idx, v, flag[0]);
}

// ---------------- clustering ----------------
__global__ void k_mu_init(const float* __restrict__ data, float* __restrict__ mu){
  int p = blockIdx.x*256 + threadIdx.x;
  if (p >= KCL*64) return;
  int k = p >> 6, f = p & 63;
  mu[p] = data[(size_t)k*(NN/KCL)*64 + f];   // init_idx = k*(N//K)
}

__global__ __launch_bounds__(128) void k_cluster_accum(const float* __restrict__ data,
    const float* __restrict__ mu, float* csum, float* cr, const int* nit, int iter)
{
  if (iter >= nit[0]) return;
  __shared__ float dt[128][65];
  __shared__ float rl[128][KCL];
  __shared__ float ms[KCL*64];
  int tid = threadIdx.x;
  int rowbase = blockIdx.x*128;
  for (int j=tid; j<KCL*64; j+=128) ms[j] = mu[j];
  for (int j=tid; j<128*64; j+=128){
    int rr = j>>6, f = j&63;
    int row = rowbase + rr;
    dt[rr][f] = (row<NN) ? data[(size_t)row*64+f] : 0.f;
  }
  __syncthreads();
  {
    int row = rowbase + tid;
    float dot[KCL];
    #pragma unroll
    for (int k2=0;k2<KCL;k2++) dot[k2]=0.f;
    for (int f=0; f<64; f++){
      float a = dt[tid][f];
      #pragma unroll
      for (int k2=0;k2<KCL;k2++) dot[k2] = fmaf(a, ms[k2*64+f], dot[k2]);
    }
    float m = -1e30f;
    #pragma unroll
    for (int k2=0;k2<KCL;k2++) m = fmaxf(m, 5.0f*dot[k2]);
    float s = 0.f, ev[KCL];
    #pragma unroll
    for (int k2=0;k2<KCL;k2++){ ev[k2] = expf(5.0f*dot[k2]-m); s += ev[k2]; }
    float inv = 1.0f/s;
    #pragma unroll
    for (int k2=0;k2<KCL;k2++) rl[tid][k2] = (row<NN) ? ev[k2]*inv : 0.f;
  }
  __syncthreads();
  for (int p=tid; p<KCL*64; p+=128){
    int k2 = p>>6, f = p&63;
    float acc = 0.f;
    for (int r2=0;r2<128;r2++) acc += rl[r2][k2]*dt[r2][f];
    unsafeAtomicAdd(&csum[p], acc);
  }
  if (tid < KCL){
    float acc = 0.f;
    for (int r2=0;r2<128;r2++) acc += rl[r2][tid];
    unsafeAtomicAdd(&cr[tid], acc);
  }
}

__global__ void k_mu_update(float* mu, float* csum, float* cr, const int* nit, int iter){
  if (iter >= nit[0]) return;
  int p = threadIdx.x;        // launched with exactly 640 threads
  float c = csum[p];
  float r = cr[p>>6];
  __syncthreads();
  mu[p] = c / r;
  csum[p] = 0.f;
  if (p < KCL) cr[p] = 0.f;
}

__global__ __launch_bounds__(128) void k_cluster_final(const float* __restrict__ data,
    const float* __restrict__ mu, void* __restrict__ out, const int* __restrict__ flag)
{
  __shared__ float dt[128][65];
  __shared__ float ms[KCL*64];
  int tid = threadIdx.x;
  int rowbase = blockIdx.x*128;
  for (int j=tid; j<KCL*64; j+=128) ms[j] = mu[j];
  for (int j=tid; j<128*64; j+=128){
    int rr = j>>6, f = j&63;
    int row = rowbase + rr;
    dt[rr][f] = (row<NN) ? data[(size_t)row*64+f] : 0.f;
  }
  __syncthreads();
  int row = rowbase + tid;
  if (row >= NN) return;
  int isbf = flag[0];
  float dot[KCL];
  #pragma unroll
  for (int k2=0;k2<KCL;k2++) dot[k2]=0.f;
  for (int f=0; f<64; f++){
    float a = dt[tid][f];
    #pragma unroll
    for (int k2=0;k2<KCL;k2++) dot[k2] = fmaf(a, ms[k2*64+f], dot[k2]);
  }
  float m = -1e30f;
  #pragma unroll
  for (int k2=0;k2<KCL;k2++) m = fmaxf(m, 5.0f*dot[k2]);
  float s = 0.f, ev[KCL];
  #pragma unroll
  for (int k2=0;k2<KCL;k2++){ ev[k2] = expf(5.0f*dot[k2]-m); s += ev[k2]; }
  float inv = 1.0f/s;
  #pragma unroll
  for (int k2=0;k2<KCL;k2++){
    stf(out, (size_t)D_OFF + (size_t)row*KCL + k2, dot[k2],     isbf);
    stf(out, (size_t)R_OFF + (size_t)row*KCL + k2, ev[k2]*inv,  isbf);
  }
}

__global__ void k_mu_out(const float* __restrict__ mu, void* __restrict__ out,
                         const int* __restrict__ flag){
  int p = blockIdx.x*256 + threadIdx.x;
  if (p < KCL*64) stf(out, MU_OFF + p, mu[p], flag[0]);
}

// ---------------- launch ----------------
extern "C" void kernel_launch(void* const* d_in, const int* in_sizes, int n_in,
                              void* d_out, int out_size, void* d_ws, size_t ws_size,
                              hipStream_t stream)
{
  const void* x   = d_in[0];
  const int*  ei  = (const int*)d_in[1];
  const int*  hv  = (const int*)d_in[2];
  const int*  he  = (const int*)d_in[3];
  const void* gW1 = d_in[4];
  const void* gb1 = d_in[5];
  const void* gW2 = d_in[6];
  const void* gb2 = d_in[7];
  const void* hW1 = d_in[8];
  const void* hb1 = d_in[9];
  const void* hW2 = d_in[10];
  const void* hb2 = d_in[11];
  const int*  nit = (const int*)d_in[12];

  float* ws = (float*)d_ws;
  size_t o = 0;
  float* BA   = ws + o; o += (size_t)NN*128;   // GEMM out (bf16 view) / data f32
  float* BB   = ws + o; o += (size_t)NN*128;   // x1 / x2 (f32)
  float* BC   = ws + o; o += (size_t)NN*128;   // x3 / x4 (f32)
  float* BD   = ws + o; o += (size_t)NEH*128;  // e_feat (bf16 view)
  float* dinv = ws + o; o += 50048;
  float* invd = ws + o; o += 50048;
  float* invv = ws + o; o += 50048;
  float* inve = ws + o; o += 10048;
  float* mu   = ws + o; o += 640;
  float* csum = ws + o; o += 640;
  float* cr   = ws + o; o += 64;
  int*   dflg = (int*)(ws + o); o += 16;
  u16* BAb = (u16*)BA;            // bf16 staging views
  u16* BDb = (u16*)BD;
  // int region (CSR)
  int* ib = (int*)(ws + o);
  size_t io = 0;
  int* cg    = ib + io; io += NN;       // counts (contiguous for one memset)
  int* cv    = ib + io; io += NN;
  int* ce    = ib + io; io += NEH + 48;
  size_t cnt_ints = io;
  int* rp_g  = ib + io; io += NN;
  int* rp_v  = ib + io; io += NN;
  int* rp_e  = ib + io; io += NEH + 48;
  int* cu_g  = ib + io; io += NN;
  int* cu_v  = ib + io; io += NN;
  int* cu_e  = ib + io; io += NEH + 48;
  int* csr_g = ib + io; io += EE;
  int* csr_e = ib + io; io += NINC;     // per-hyperedge vertex lists
  int* csr_v = ib + io; io += NINC;     // per-vertex hyperedge lists
  int* bs_g  = ib + io; io += 256;
  int* bs_v  = ib + io; io += 256;
  int* bs_e  = ib + io; io += 256;

  const int* srcp = ei;
  const int* dstp = ei + EE;
  dim3 B(256);
  const int NBN = (NN + 255)/256;       // 196
  const int NBE = (NEH + 255)/256;      // 40

  // dtype detection
  k_detect<<<dim3(1), B, 0, stream>>>((const u16*)x, dflg);

  // ---- CSR build ----
  hipMemsetAsync(cg, 0, cnt_ints*sizeof(int), stream);
  k_cnt <<<dim3((EE+255)/256), B, 0, stream>>>(dstp, hv, he, cg, cv, ce);
  k_invs<<<dim3(NBN), B, 0, stream>>>(cg, cv, ce, dinv, invd, invv, inve);
  k_scan1<<<dim3(NBN), B, 0, stream>>>(cg, rp_g, bs_g, NN);
  k_scan2<<<dim3(1),   B, 0, stream>>>(bs_g, NBN);
  k_scan3<<<dim3(NBN), B, 0, stream>>>(rp_g, cu_g, bs_g, NN);
  k_scan1<<<dim3(NBN), B, 0, stream>>>(cv, rp_v, bs_v, NN);
  k_scan2<<<dim3(1),   B, 0, stream>>>(bs_v, NBN);
  k_scan3<<<dim3(NBN), B, 0, stream>>>(rp_v, cu_v, bs_v, NN);
  k_scan1<<<dim3(NBE), B, 0, stream>>>(ce, rp_e, bs_e, NEH);
  k_scan2<<<dim3(1),   B, 0, stream>>>(bs_e, NBE);
  k_scan3<<<dim3(NBE), B, 0, stream>>>(rp_e, cu_e, bs_e, NEH);
  k_fill_gcn<<<dim3((EE+255)/256),   B, 0, stream>>>(srcp, dstp, cu_g, csr_g);
  k_fill_hg <<<dim3((NINC+255)/256), B, 0, stream>>>(hv, he, cu_e, csr_e, cu_v, csr_v);

  const int NB = (NN + 63)/64;          // 782 blocks (BM=64)
  // ---- GCN layer 1: BAb = bf16(x@gW1) ; x1(BB) = gather + gb1, relu ----
  k_gemmv2<256,128,true,true><<<dim3(NB), B, 0, stream>>>(x, gW1, nullptr, BAb, NN, 0, dflg);
  k_gcn_gather<128><<<dim3(NN), dim3(128), 0, stream>>>(rp_g, cg, csr_g, dinv, invd,
                                                        BAb, gb1, BB, 1, dflg);
  // ---- HGNNP layer 1: BAb = bf16(x@hW1+hb1) ; ef(BDb) ; x3(BC) relu ----
  k_gemmv2<256,128,true,true><<<dim3(NB), B, 0, stream>>>(x, hW1, hb1, BAb, NN, 0, dflg);
  k_hg_e_gather<128><<<dim3(NEH), dim3(128), 0, stream>>>(rp_e, ce, csr_e, inve, BAb, BDb);
  k_hg_v_gather<128><<<dim3(NN),  dim3(128), 0, stream>>>(rp_v, cv, csr_v, invv, BDb, BC, 1);

  // ---- GCN layer 2: BAb = bf16(x1@gW2) ; x2(BB) = gather + gb2 ----
  k_gemmv2<128,64,false,true><<<dim3(NB), B, 0, stream>>>(BB, gW2, nullptr, BAb, NN, 0, dflg);
  k_gcn_gather<64><<<dim3(NN), dim3(64), 0, stream>>>(rp_g, cg, csr_g, dinv, invd,
                                                      BAb, gb2, BB, 0, dflg);
  // ---- HGNNP layer 2: BAb = bf16(x3@hW2+hb2) ; ef(BDb) ; x4(BC) ----
  k_gemmv2<128,64,false,true><<<dim3(NB), B, 0, stream>>>(BC, hW2, hb2, BAb, NN, 0, dflg);
  k_hg_e_gather<64><<<dim3(NEH), dim3(64), 0, stream>>>(rp_e, ce, csr_e, inve, BAb, BDb);
  k_hg_v_gather<64><<<dim3(NN),  dim3(64), 0, stream>>>(rp_v, cv, csr_v, invv, BDb, BC, 0);

  // ---- embeds (f32/bf16 out) + normalized rows -> data(BA f32, BAb dead) ----
  k_embeds<<<dim3((NN+3)/4), B, 0, stream>>>(BB, BC, d_out, BA, dflg);

  // ---- clustering ----
  k_mu_init<<<dim3(3), B, 0, stream>>>(BA, mu);
  hipMemsetAsync(csum, 0, (640+64)*4, stream);
  const int CB = (NN + 127)/128;
  for (int it = 0; it < 4; ++it){   // gated by iter < *num_iter (setup: 1)
    k_cluster_accum<<<dim3(CB), dim3(128), 0, stream>>>(BA, mu, csum, cr, nit, it);
    k_mu_update    <<<dim3(1),  dim3(640), 0, stream>>>(mu, csum, cr, nit, it);
  }
  k_cluster_final<<<dim3(CB), dim3(128), 0, stream>>>(BA, mu, d_out, dflg);
  k_mu_out       <<<dim3(3),  B, 0, stream>>>(mu, d_out, dflg);
}

// Round 8
// 533.878 us; speedup vs baseline: 1.2266x; 1.2266x over previous
//
#include <hip/hip_runtime.h>
#include <hip/hip_bf16.h>

// HGNNP_GCN + ClusterNet forward, MI355X (round 8).
// R7 counters: k_gemmv2 95us, VALUBusy 31%, occupancy 21% (grid-limited,
// 3 blocks/CU), HBM 5% -> latency-bound vector-FMA GEMM at 22% of f32 peak.
// This round: all GEMMs moved to v_mfma_f32_16x16x32_bf16 (bf16 inputs, f32
// accum). x and W pre-converted to bf16 (W transposed); GEMM-feeding gathers
// emit bf16. Node buffers padded to 50048 rows (= 782 blocks x 64) -> no
// bounds checks in the GEMM.

#define NN   50000   // nodes
#define NP   50048   // padded rows (782 * 64)
#define EE   800000  // directed edges
#define NINC 200000  // incidence entries
#define NEH  10000   // hyperedges
#define KCL  10      // clusters

// output element offsets (flat concat: mu | r | embeds | dist)
#define MU_OFF  0
#define R_OFF   640
#define EMB_OFF 500640
#define D_OFF   3700640

typedef __hip_bfloat16 bf16;
typedef unsigned short u16;
typedef __attribute__((ext_vector_type(8))) short short8;
typedef __attribute__((ext_vector_type(4))) float f32x4;

__device__ __forceinline__ float b2f(bf16 v){ return __bfloat162float(v); }
__device__ __forceinline__ float us2f(u16 u){ return __uint_as_float(((unsigned)u) << 16); }
__device__ __forceinline__ u16 f2bu(float f){
  unsigned u = __float_as_uint(f);
  return (u16)((u + 0x7fffu + ((u >> 16) & 1u)) >> 16);   // RNE
}
__device__ __forceinline__ bf16 f2b(float f){
  u16 r = f2bu(f);
  bf16 h;
  reinterpret_cast<u16&>(h) = r;
  return h;
}
// external-float load/store, dtype chosen by uniform runtime flag
__device__ __forceinline__ float ldf(const void* p, size_t i, int isbf){
  return isbf ? b2f(((const bf16*)p)[i]) : ((const float*)p)[i];
}
__device__ __forceinline__ void stf(void* p, size_t i, float v, int isbf){
  if (isbf) ((bf16*)p)[i] = f2b(v);
  else      ((float*)p)[i] = v;
}

// ---------------- dtype detector ----------------
__global__ void k_detect(const u16* __restrict__ xr, int* flag){
  __shared__ int bad;
  if (threadIdx.x == 0) bad = 0;
  __syncthreads();
  for (int i = threadIdx.x; i < 4096; i += 256){
    int e = (xr[i] >> 7) & 0xFF;
    if (e >= 0xEF) bad = 1;     // f32 low-halves have random exponents
  }
  __syncthreads();
  if (threadIdx.x == 0) *flag = bad ? 0 : 1;   // 1 = bf16, 0 = f32
}

// ---------------- input prep: x -> bf16, W -> bf16 transposed, biases -> f32 ----------------
__global__ void k_aconv(const void* __restrict__ x, u16* __restrict__ xb,
                        const int* __restrict__ flag){
  int i = blockIdx.x*256 + threadIdx.x;      // one ushort4 (4 elems)
  const int n4 = NN*256/4;                   // 3,200,000
  if (i >= n4) return;
  ushort4 o;
  if (flag[0]){
    o = ((const ushort4*)x)[i];
  } else {
    float4 v = ((const float4*)x)[i];
    o = make_ushort4(f2bu(v.x), f2bu(v.y), f2bu(v.z), f2bu(v.w));
  }
  ((ushort4*)xb)[i] = o;
}

__global__ void k_wprep(const void* gW1, const void* hW1, const void* gW2, const void* hW2,
                        const void* gb1, const void* hb1, const void* gb2, const void* hb2,
                        u16* gW1t, u16* hW1t, u16* gW2t, u16* hW2t,
                        float* gb1f, float* hb1f, float* gb2f, float* hb2f,
                        const int* __restrict__ flag){
  const int isbf = flag[0];
  int i = blockIdx.x*256 + threadIdx.x;
  if (i < 256*128){                    // Wt[n][k] = W[k][n], 128x256
    int n = i >> 8, k = i & 255;
    gW1t[i] = f2bu(ldf(gW1, (size_t)k*128 + n, isbf));
    hW1t[i] = f2bu(ldf(hW1, (size_t)k*128 + n, isbf));
  }
  if (i < 64*128){                     // 64x128
    int n = i >> 7, k = i & 127;
    gW2t[i] = f2bu(ldf(gW2, (size_t)k*64 + n, isbf));
    hW2t[i] = f2bu(ldf(hW2, (size_t)k*64 + n, isbf));
  }
  if (i < 128){ gb1f[i] = ldf(gb1,i,isbf); hb1f[i] = ldf(hb1,i,isbf); }
  if (i < 64) { gb2f[i] = ldf(gb2,i,isbf); hb2f[i] = ldf(hb2,i,isbf); }
}

// ---------------- CSR build: count / scan / fill ----------------
__global__ void k_cnt(const int* __restrict__ dst, const int* __restrict__ hv,
                      const int* __restrict__ he, int* cg, int* cv, int* ce){
  int i = blockIdx.x*256 + threadIdx.x;
  if (i < EE)   atomicAdd(&cg[dst[i]], 1);
  if (i < NINC){ atomicAdd(&cv[hv[i]], 1); atomicAdd(&ce[he[i]], 1); }
}

__global__ void k_invs(const int* __restrict__ cg, const int* __restrict__ cv,
                       const int* __restrict__ ce,
                       float* dinv, float* invd, float* invv, float* inve){
  int i = blockIdx.x*256 + threadIdx.x;
  if (i < NN){
    float d = 1.0f + (float)cg[i];     // self-loop included
    dinv[i] = rsqrtf(d);
    invd[i] = 1.0f / d;
    invv[i] = 1.0f / fmaxf((float)cv[i], 1.0f);
  }
  if (i < NEH) inve[i] = 1.0f / fmaxf((float)ce[i], 1.0f);
}

// exclusive scan, 256 elems/block (Hillis-Steele in LDS)
__global__ void k_scan1(const int* __restrict__ in, int* __restrict__ out,
                        int* __restrict__ bsum, int n){
  __shared__ int s[256];
  int t = threadIdx.x, i = blockIdx.x*256 + t;
  int v = (i < n) ? in[i] : 0;
  s[t] = v; __syncthreads();
  #pragma unroll
  for (int off = 1; off < 256; off <<= 1){
    int add = (t >= off) ? s[t-off] : 0;
    __syncthreads();
    s[t] += add;
    __syncthreads();
  }
  if (i < n) out[i] = s[t] - v;        // exclusive
  if (t == 255) bsum[blockIdx.x] = s[255];
}

__global__ void k_scan2(int* bsum, int nb){   // single block, nb <= 256
  __shared__ int s[256];
  int t = threadIdx.x;
  int v = (t < nb) ? bsum[t] : 0;
  s[t] = v; __syncthreads();
  #pragma unroll
  for (int off = 1; off < 256; off <<= 1){
    int add = (t >= off) ? s[t-off] : 0;
    __syncthreads();
    s[t] += add;
    __syncthreads();
  }
  if (t < nb) bsum[t] = s[t] - v;
}

__global__ void k_scan3(int* __restrict__ rp, int* __restrict__ cur,
                        const int* __restrict__ bsum, int n){
  int i = blockIdx.x*256 + threadIdx.x;
  if (i < n){ int v = rp[i] + bsum[blockIdx.x]; rp[i] = v; cur[i] = v; }
}

__global__ void k_fill_gcn(const int* __restrict__ src, const int* __restrict__ dst,
                           int* cur, int* __restrict__ csr){
  int i = blockIdx.x*256 + threadIdx.x;
  if (i < EE){ int p = atomicAdd(&cur[dst[i]], 1); csr[p] = src[i]; }
}

__global__ void k_fill_hg(const int* __restrict__ hv, const int* __restrict__ he,
                          int* cur_e, int* __restrict__ csr_e,
                          int* cur_v, int* __restrict__ csr_v){
  int i = blockIdx.x*256 + threadIdx.x;
  if (i < NINC){
    int v = hv[i], e = he[i];
    csr_e[atomicAdd(&cur_e[e], 1)] = v;
    csr_v[atomicAdd(&cur_v[v], 1)] = e;
  }
}

// ---------------- MFMA GEMM: C[NP][NCOL] = A[NP][KDIM] @ Wt[NCOL][KDIM]^T ----------------
// A, Wt bf16; C bf16; f32 accumulate via v_mfma_f32_16x16x32_bf16.
// 256 thr = 4 waves; block tile 64 rows x NCOL cols; wave w owns rows w*16..+16.
// Verified layouts (learn_hip m89/m91): C/D col=lane&15,row=(lane>>4)*4+reg;
// A lane holds [lane&15][(lane>>4)*8+e]; B lane holds [(lane>>4)*8+e][lane&15].
template<int KDIM, int NCOL>
__global__ __launch_bounds__(256) void k_gemm_mfma(
    const u16* __restrict__ A, const u16* __restrict__ Wt,
    const float* __restrict__ bias, u16* __restrict__ C, int relu)
{
  constexpr int NT  = NCOL/16;      // col tiles per wave (8 or 4)
  constexpr int LDA = 40;           // lds row stride (bf16): 80B = 20 banks -> 2-way max
  __shared__ __align__(16) u16 Asl[64][LDA];
  __shared__ __align__(16) u16 Wsl[NCOL][LDA];
  const int tid  = threadIdx.x;
  const int wave = tid >> 6, lane = tid & 63;
  const int l15 = lane & 15, l4 = lane >> 4;
  const int row0 = blockIdx.x * 64;
  const int ar = tid >> 2, aq = tid & 3;       // A staging: row, 8-elem chunk
  constexpr int NW = NCOL*4/256;               // W staging chunks per thread

  f32x4 acc[NT] = {};

  for (int kk = 0; kk < KDIM; kk += 32){
    { // stage A tile 64x32 (one uint4 = 8 bf16 per thread)
      uint4 v = *(const uint4*)(A + (size_t)(row0 + ar)*KDIM + kk + aq*8);
      *(uint4*)&Asl[ar][aq*8] = v;
    }
    #pragma unroll
    for (int w2 = 0; w2 < NW; ++w2){ // stage Wt tile NCOLx32
      int c = tid + w2*256;
      int n = c >> 2, q = c & 3;
      uint4 v = *(const uint4*)(Wt + (size_t)n*KDIM + kk + q*8);
      *(uint4*)&Wsl[n][q*8] = v;
    }
    __syncthreads();
    short8 af = *(const short8*)&Asl[wave*16 + l15][l4*8];
    #pragma unroll
    for (int t = 0; t < NT; ++t){
      short8 bf = *(const short8*)&Wsl[t*16 + l15][l4*8];
      acc[t] = __builtin_amdgcn_mfma_f32_16x16x32_bf16(af, bf, acc[t], 0, 0, 0);
    }
    __syncthreads();
  }

  #pragma unroll
  for (int t = 0; t < NT; ++t){
    int gcol = t*16 + l15;
    float b = bias ? bias[gcol] : 0.f;
    #pragma unroll
    for (int e = 0; e < 4; ++e){
      int grow = row0 + wave*16 + l4*4 + e;
      float v = acc[t][e] + b;
      if (relu) v = fmaxf(v, 0.f);
      C[(size_t)grow*NCOL + gcol] = f2bu(v);
    }
  }
}

// ---------------- fused GCN gather (bf16 operand): selfloop+edges+bias+relu ----------------
template<int F, bool OUTBF>
__global__ void k_gcn_gather(const int* __restrict__ rp, const int* __restrict__ cnt,
    const int* __restrict__ csr, const float* __restrict__ dinv,
    const float* __restrict__ invd, const u16* __restrict__ h,
    const float* __restrict__ bias, void* __restrict__ out, int relu)
{
  int d = blockIdx.x, j = threadIdx.x;
  float acc = us2f(h[(size_t)d*F + j]) * invd[d];   // self-loop term
  const float dd = dinv[d];
  int k = rp[d], e = k + cnt[d];
  for (; k < e; ++k){
    int s = csr[k];                                 // broadcast across block
    acc = fmaf(us2f(h[(size_t)s*F + j]), dinv[s]*dd, acc);
  }
  acc += bias[j];
  if (relu) acc = fmaxf(acc, 0.f);
  if (OUTBF) ((u16*)out)[(size_t)d*F + j] = f2bu(acc);
  else       ((float*)out)[(size_t)d*F + j] = acc;
}

// ---------------- fused hypergraph gathers (mean, bf16 operands) ----------------
template<int F>
__global__ void k_hg_e_gather(const int* __restrict__ rp, const int* __restrict__ cnt,
    const int* __restrict__ csr, const float* __restrict__ inve,
    const u16* __restrict__ h, u16* __restrict__ ef)
{
  int e = blockIdx.x, j = threadIdx.x;
  int k = rp[e], n = cnt[e];
  float acc = 0.f;
  for (int t = 0; t < n; ++t)
    acc += us2f(h[(size_t)csr[k+t]*F + j]);
  ef[(size_t)e*F + j] = f2bu(acc * inve[e]);
}

template<int F, bool OUTBF>
__global__ void k_hg_v_gather(const int* __restrict__ rp, const int* __restrict__ cnt,
    const int* __restrict__ csr, const float* __restrict__ invv,
    const u16* __restrict__ ef, void* __restrict__ out, int relu)
{
  int v = blockIdx.x, j = threadIdx.x;
  int k = rp[v], n = cnt[v];
  float acc = 0.f;
  for (int t = 0; t < n; ++t)
    acc += us2f(ef[(size_t)csr[k+t]*F + j]);
  acc *= invv[v];
  if (relu) acc = fmaxf(acc, 0.f);
  if (OUTBF) ((u16*)out)[(size_t)v*F + j] = f2bu(acc);
  else       ((float*)out)[(size_t)v*F + j] = acc;
}

// ---------------- embeds + row normalize ----------------
__global__ void k_embeds(const float* __restrict__ x2, const float* __restrict__ x4,
                         void* __restrict__ out, float* __restrict__ data,
                         const int* __restrict__ flag){
  int row  = blockIdx.x*4 + (threadIdx.x >> 6);
  int lane = threadIdx.x & 63;
  if (row >= NN) return;
  size_t idx = (size_t)row*64 + lane;
  float v = 0.5f*(x2[idx] + x4[idx]);
  float ss = v*v;
  #pragma unroll
  for (int off=32; off>0; off>>=1) ss += __shfl_xor(ss, off);
  float inv = rsqrtf(ss);
  data[idx] = v*inv;
  stf(out, EMB_OFF + idx, v, flag[0]);
}

// ---------------- clustering ----------------
__global__ void k_mu_init(const float* __restrict__ data, float* __restrict__ mu){
  int p = blockIdx.x*256 + threadIdx.x;
  if (p >= KCL*64) return;
  int k = p >> 6, f = p & 63;
  mu[p] = data[(size_t)k*(NN/KCL)*64 + f];   // init_idx = k*(N//K)
}

__global__ __launch_bounds__(128) void k_cluster_accum(const float* __restrict__ data,
    const float* __restrict__ mu, float* csum, float* cr, const int* nit, int iter)
{
  if (iter >= nit[0]) return;
  __shared__ float dt[128][65];
  __shared__ float rl[128][KCL];
  __shared__ float ms[KCL*64];
  int tid = threadIdx.x;
  int rowbase = blockIdx.x*128;
  for (int j=tid; j<KCL*64; j+=128) ms[j] = mu[j];
  for (int j=tid; j<128*64; j+=128){
    int rr = j>>6, f = j&63;
    int row = rowbase + rr;
    dt[rr][f] = (row<NN) ? data[(size_t)row*64+f] : 0.f;
  }
  __syncthreads();
  {
    int row = rowbase + tid;
    float dot[KCL];
    #pragma unroll
    for (int k2=0;k2<KCL;k2++) dot[k2]=0.f;
    for (int f=0; f<64; f++){
      float a = dt[tid][f];
      #pragma unroll
      for (int k2=0;k2<KCL;k2++) dot[k2] = fmaf(a, ms[k2*64+f], dot[k2]);
    }
    float m = -1e30f;
    #pragma unroll
    for (int k2=0;k2<KCL;k2++) m = fmaxf(m, 5.0f*dot[k2]);
    float s = 0.f, ev[KCL];
    #pragma unroll
    for (int k2=0;k2<KCL;k2++){ ev[k2] = expf(5.0f*dot[k2]-m); s += ev[k2]; }
    float inv = 1.0f/s;
    #pragma unroll
    for (int k2=0;k2<KCL;k2++) rl[tid][k2] = (row<NN) ? ev[k2]*inv : 0.f;
  }
  __syncthreads();
  for (int p=tid; p<KCL*64; p+=128){
    int k2 = p>>6, f = p&63;
    float acc = 0.f;
    for (int r2=0;r2<128;r2++) acc += rl[r2][k2]*dt[r2][f];
    unsafeAtomicAdd(&csum[p], acc);
  }
  if (tid < KCL){
    float acc = 0.f;
    for (int r2=0;r2<128;r2++) acc += rl[r2][tid];
    unsafeAtomicAdd(&cr[tid], acc);
  }
}

__global__ void k_mu_update(float* mu, float* csum, float* cr, const int* nit, int iter){
  if (iter >= nit[0]) return;
  int p = threadIdx.x;        // launched with exactly 640 threads
  float c = csum[p];
  float r = cr[p>>6];
  __syncthreads();
  mu[p] = c / r;
  csum[p] = 0.f;
  if (p < KCL) cr[p] = 0.f;
}

__global__ __launch_bounds__(128) void k_cluster_final(const float* __restrict__ data,
    const float* __restrict__ mu, void* __restrict__ out, const int* __restrict__ flag)
{
  __shared__ float dt[128][65];
  __shared__ float ms[KCL*64];
  int tid = threadIdx.x;
  int rowbase = blockIdx.x*128;
  for (int j=tid; j<KCL*64; j+=128) ms[j] = mu[j];
  for (int j=tid; j<128*64; j+=128){
    int rr = j>>6, f = j&63;
    int row = rowbase + rr;
    dt[rr][f] = (row<NN) ? data[(size_t)row*64+f] : 0.f;
  }
  __syncthreads();
  int row = rowbase + tid;
  if (row >= NN) return;
  int isbf = flag[0];
  float dot[KCL];
  #pragma unroll
  for (int k2=0;k2<KCL;k2++) dot[k2]=0.f;
  for (int f=0; f<64; f++){
    float a = dt[tid][f];
    #pragma unroll
    for (int k2=0;k2<KCL;k2++) dot[k2] = fmaf(a, ms[k2*64+f], dot[k2]);
  }
  float m = -1e30f;
  #pragma unroll
  for (int k2=0;k2<KCL;k2++) m = fmaxf(m, 5.0f*dot[k2]);
  float s = 0.f, ev[KCL];
  #pragma unroll
  for (int k2=0;k2<KCL;k2++){ ev[k2] = expf(5.0f*dot[k2]-m); s += ev[k2]; }
  float inv = 1.0f/s;
  #pragma unroll
  for (int k2=0;k2<KCL;k2++){
    stf(out, (size_t)D_OFF + (size_t)row*KCL + k2, dot[k2],     isbf);
    stf(out, (size_t)R_OFF + (size_t)row*KCL + k2, ev[k2]*inv,  isbf);
  }
}

__global__ void k_mu_out(const float* __restrict__ mu, void* __restrict__ out,
                         const int* __restrict__ flag){
  int p = blockIdx.x*256 + threadIdx.x;
  if (p < KCL*64) stf(out, MU_OFF + p, mu[p], flag[0]);
}

// ---------------- launch ----------------
extern "C" void kernel_launch(void* const* d_in, const int* in_sizes, int n_in,
                              void* d_out, int out_size, void* d_ws, size_t ws_size,
                              hipStream_t stream)
{
  const void* x   = d_in[0];
  const int*  ei  = (const int*)d_in[1];
  const int*  hv  = (const int*)d_in[2];
  const int*  he  = (const int*)d_in[3];
  const void* gW1 = d_in[4];
  const void* gb1 = d_in[5];
  const void* gW2 = d_in[6];
  const void* gb2 = d_in[7];
  const void* hW1 = d_in[8];
  const void* hb1 = d_in[9];
  const void* hW2 = d_in[10];
  const void* hb2 = d_in[11];
  const int*  nit = (const int*)d_in[12];

  float* ws = (float*)d_ws;
  size_t o = 0;
  // xb: NP x 256 bf16 (= NP*128 f32 slots); later reused: x2f | x4f (f32 NP x 64 each)
  u16*   xb  = (u16*)(ws + o); o += (size_t)NP*128;
  u16*   BAb = (u16*)(ws + o); o += (size_t)NP*64;    // GEMM out bf16 NP x 128
  u16*   BBb = (u16*)(ws + o); o += (size_t)NP*64;    // x1 bf16; later dataf f32 NP x 64
  u16*   BCb = (u16*)(ws + o); o += (size_t)NP*64;    // x3 bf16
  u16*   BDb = (u16*)(ws + o); o += (size_t)NEH*64;   // e_feat bf16 NEH x 128
  u16*  gW1t = (u16*)(ws + o); o += 16384;            // 128x256 bf16
  u16*  hW1t = (u16*)(ws + o); o += 16384;
  u16*  gW2t = (u16*)(ws + o); o += 4096;             // 64x128 bf16
  u16*  hW2t = (u16*)(ws + o); o += 4096;
  float* gb1f = ws + o; o += 128;
  float* hb1f = ws + o; o += 128;
  float* gb2f = ws + o; o += 64;
  float* hb2f = ws + o; o += 64;
  float* dinv = ws + o; o += 50048;
  float* invd = ws + o; o += 50048;
  float* invv = ws + o; o += 50048;
  float* inve = ws + o; o += 10048;
  float* mu   = ws + o; o += 640;
  float* csum = ws + o; o += 640;
  float* cr   = ws + o; o += 64;
  int*   dflg = (int*)(ws + o); o += 16;
  float* x2f   = (float*)xb;                 // aliases (xb dead by then)
  float* x4f   = (float*)xb + (size_t)NP*64;
  float* dataf = (float*)BBb;                // alias (BBb dead by then)
  // int region (CSR)
  int* ib = (int*)(ws + o);
  size_t io = 0;
  int* cg    = ib + io; io += NN;       // counts (contiguous for one memset)
  int* cv    = ib + io; io += NN;
  int* ce    = ib + io; io += NEH + 48;
  size_t cnt_ints = io;
  int* rp_g  = ib + io; io += NN;
  int* rp_v  = ib + io; io += NN;
  int* rp_e  = ib + io; io += NEH + 48;
  int* cu_g  = ib + io; io += NN;
  int* cu_v  = ib + io; io += NN;
  int* cu_e  = ib + io; io += NEH + 48;
  int* csr_g = ib + io; io += EE;
  int* csr_e = ib + io; io += NINC;
  int* csr_v = ib + io; io += NINC;
  int* bs_g  = ib + io; io += 256;
  int* bs_v  = ib + io; io += 256;
  int* bs_e  = ib + io; io += 256;

  const int* srcp = ei;
  const int* dstp = ei + EE;
  dim3 B(256);
  const int NBN = (NN + 255)/256;       // 196
  const int NBE = (NEH + 255)/256;      // 40

  // dtype detection + input prep
  k_detect<<<dim3(1), B, 0, stream>>>((const u16*)x, dflg);
  k_aconv<<<dim3(12500), B, 0, stream>>>(x, xb, dflg);
  k_wprep<<<dim3(128), B, 0, stream>>>(gW1, hW1, gW2, hW2, gb1, hb1, gb2, hb2,
                                       gW1t, hW1t, gW2t, hW2t,
                                       gb1f, hb1f, gb2f, hb2f, dflg);

  // ---- CSR build ----
  hipMemsetAsync(cg, 0, cnt_ints*sizeof(int), stream);
  k_cnt <<<dim3((EE+255)/256), B, 0, stream>>>(dstp, hv, he, cg, cv, ce);
  k_invs<<<dim3(NBN), B, 0, stream>>>(cg, cv, ce, dinv, invd, invv, inve);
  k_scan1<<<dim3(NBN), B, 0, stream>>>(cg, rp_g, bs_g, NN);
  k_scan2<<<dim3(1),   B, 0, stream>>>(bs_g, NBN);
  k_scan3<<<dim3(NBN), B, 0, stream>>>(rp_g, cu_g, bs_g, NN);
  k_scan1<<<dim3(NBN), B, 0, stream>>>(cv, rp_v, bs_v, NN);
  k_scan2<<<dim3(1),   B, 0, stream>>>(bs_v, NBN);
  k_scan3<<<dim3(NBN), B, 0, stream>>>(rp_v, cu_v, bs_v, NN);
  k_scan1<<<dim3(NBE), B, 0, stream>>>(ce, rp_e, bs_e, NEH);
  k_scan2<<<dim3(1),   B, 0, stream>>>(bs_e, NBE);
  k_scan3<<<dim3(NBE), B, 0, stream>>>(rp_e, cu_e, bs_e, NEH);
  k_fill_gcn<<<dim3((EE+255)/256),   B, 0, stream>>>(srcp, dstp, cu_g, csr_g);
  k_fill_hg <<<dim3((NINC+255)/256), B, 0, stream>>>(hv, he, cu_e, csr_e, cu_v, csr_v);

  const int NB = NP/64;                 // 782 MFMA blocks
  // ---- GCN layer 1 ----
  k_gemm_mfma<256,128><<<dim3(NB), B, 0, stream>>>(xb, gW1t, nullptr, BAb, 0);
  k_gcn_gather<128,true><<<dim3(NN), dim3(128), 0, stream>>>(rp_g, cg, csr_g, dinv, invd,
                                                             BAb, gb1f, BBb, 1);
  // ---- HGNNP layer 1 ----
  k_gemm_mfma<256,128><<<dim3(NB), B, 0, stream>>>(xb, hW1t, hb1f, BAb, 0);
  k_hg_e_gather<128><<<dim3(NEH), dim3(128), 0, stream>>>(rp_e, ce, csr_e, inve, BAb, BDb);
  k_hg_v_gather<128,true><<<dim3(NN), dim3(128), 0, stream>>>(rp_v, cv, csr_v, invv, BDb, BCb, 1);

  // ---- GCN layer 2 ----
  k_gemm_mfma<128,64><<<dim3(NB), B, 0, stream>>>(BBb, gW2t, nullptr, BAb, 0);
  k_gcn_gather<64,false><<<dim3(NN), dim3(64), 0, stream>>>(rp_g, cg, csr_g, dinv, invd,
                                                            BAb, gb2f, x2f, 0);
  // ---- HGNNP layer 2 ----
  k_gemm_mfma<128,64><<<dim3(NB), B, 0, stream>>>(BCb, hW2t, hb2f, BAb, 0);
  k_hg_e_gather<64><<<dim3(NEH), dim3(64), 0, stream>>>(rp_e, ce, csr_e, inve, BAb, BDb);
  k_hg_v_gather<64,false><<<dim3(NN), dim3(64), 0, stream>>>(rp_v, cv, csr_v, invv, BDb, x4f, 0);

  // ---- embeds + normalized rows -> dataf ----
  k_embeds<<<dim3((NN+3)/4), B, 0, stream>>>(x2f, x4f, d_out, dataf, dflg);

  // ---- clustering ----
  k_mu_init<<<dim3(3), B, 0, stream>>>(dataf, mu);
  hipMemsetAsync(csum, 0, (640+64)*4, stream);
  const int CB = (NN + 127)/128;
  for (int it = 0; it < 4; ++it){   // gated by iter < *num_iter (setup: 1)
    k_cluster_accum<<<dim3(CB), dim3(128), 0, stream>>>(dataf, mu, csum, cr, nit, it);
    k_mu_update    <<<dim3(1),  dim3(640), 0, stream>>>(mu, csum, cr, nit, it);
  }
  k_cluster_final<<<dim3(CB), dim3(128), 0, stream>>>(dataf, mu, d_out, dflg);
  k_mu_out       <<<dim3(3),  B, 0, stream>>>(mu, d_out, dflg);
}

// Round 9
// 426.812 us; speedup vs baseline: 1.5343x; 1.2508x over previous
//
#include <hip/hip_runtime.h>
#include <hip/hip_bf16.h>

// HGNNP_GCN + ClusterNet forward, MI355X (round 9).
// R8 counters: k_gcn_gather<128> 89us with FETCH halved vs R6 but time flat
// -> not traffic-bound; latency-chain bound (csr[k] -> dependent gather per
// iteration). This round: (1) wave-broadcast index staging (1 coalesced load
// per 64 edges + __shfl), (2) 4-way unrolled independent gathers, (3) dinv
// pre-scaled into GEMM epilogue so the per-edge weight load vanishes.
// One wave per destination row, 4 rows per 256-thread block.

#define NN   50000   // nodes (= 12500*4)
#define NP   50048   // padded rows (782 * 64)
#define EE   800000  // directed edges
#define NINC 200000  // incidence entries
#define NEH  10000   // hyperedges (= 2500*4)
#define KCL  10      // clusters

// output element offsets (flat concat: mu | r | embeds | dist)
#define MU_OFF  0
#define R_OFF   640
#define EMB_OFF 500640
#define D_OFF   3700640

typedef __hip_bfloat16 bf16;
typedef unsigned short u16;
typedef __attribute__((ext_vector_type(8))) short short8;
typedef __attribute__((ext_vector_type(4))) float f32x4;

__device__ __forceinline__ float b2f(bf16 v){ return __bfloat162float(v); }
__device__ __forceinline__ float us2f(u16 u){ return __uint_as_float(((unsigned)u) << 16); }
__device__ __forceinline__ u16 f2bu(float f){
  unsigned u = __float_as_uint(f);
  return (u16)((u + 0x7fffu + ((u >> 16) & 1u)) >> 16);   // RNE
}
__device__ __forceinline__ bf16 f2b(float f){
  u16 r = f2bu(f);
  bf16 h;
  reinterpret_cast<u16&>(h) = r;
  return h;
}
__device__ __forceinline__ float ldf(const void* p, size_t i, int isbf){
  return isbf ? b2f(((const bf16*)p)[i]) : ((const float*)p)[i];
}
__device__ __forceinline__ void stf(void* p, size_t i, float v, int isbf){
  if (isbf) ((bf16*)p)[i] = f2b(v);
  else      ((float*)p)[i] = v;
}

// ---------------- dtype detector ----------------
__global__ void k_detect(const u16* __restrict__ xr, int* flag){
  __shared__ int bad;
  if (threadIdx.x == 0) bad = 0;
  __syncthreads();
  for (int i = threadIdx.x; i < 4096; i += 256){
    int e = (xr[i] >> 7) & 0xFF;
    if (e >= 0xEF) bad = 1;     // f32 low-halves have random exponents
  }
  __syncthreads();
  if (threadIdx.x == 0) *flag = bad ? 0 : 1;   // 1 = bf16, 0 = f32
}

// ---------------- input prep ----------------
__global__ void k_aconv(const void* __restrict__ x, u16* __restrict__ xb,
                        const int* __restrict__ flag){
  int i = blockIdx.x*256 + threadIdx.x;      // one ushort4 (4 elems)
  const int n4 = NN*256/4;
  if (i >= n4) return;
  ushort4 o;
  if (flag[0]){
    o = ((const ushort4*)x)[i];
  } else {
    float4 v = ((const float4*)x)[i];
    o = make_ushort4(f2bu(v.x), f2bu(v.y), f2bu(v.z), f2bu(v.w));
  }
  ((ushort4*)xb)[i] = o;
}

__global__ void k_wprep(const void* gW1, const void* hW1, const void* gW2, const void* hW2,
                        const void* gb1, const void* hb1, const void* gb2, const void* hb2,
                        u16* gW1t, u16* hW1t, u16* gW2t, u16* hW2t,
                        float* gb1f, float* hb1f, float* gb2f, float* hb2f,
                        const int* __restrict__ flag){
  const int isbf = flag[0];
  int i = blockIdx.x*256 + threadIdx.x;
  if (i < 256*128){                    // Wt[n][k] = W[k][n], 128x256
    int n = i >> 8, k = i & 255;
    gW1t[i] = f2bu(ldf(gW1, (size_t)k*128 + n, isbf));
    hW1t[i] = f2bu(ldf(hW1, (size_t)k*128 + n, isbf));
  }
  if (i < 64*128){                     // 64x128
    int n = i >> 7, k = i & 127;
    gW2t[i] = f2bu(ldf(gW2, (size_t)k*64 + n, isbf));
    hW2t[i] = f2bu(ldf(hW2, (size_t)k*64 + n, isbf));
  }
  if (i < 128){ gb1f[i] = ldf(gb1,i,isbf); hb1f[i] = ldf(hb1,i,isbf); }
  if (i < 64) { gb2f[i] = ldf(gb2,i,isbf); hb2f[i] = ldf(hb2,i,isbf); }
}

// ---------------- CSR build: count / scan / fill ----------------
__global__ void k_cnt(const int* __restrict__ dst, const int* __restrict__ hv,
                      const int* __restrict__ he, int* cg, int* cv, int* ce){
  int i = blockIdx.x*256 + threadIdx.x;
  if (i < EE)   atomicAdd(&cg[dst[i]], 1);
  if (i < NINC){ atomicAdd(&cv[hv[i]], 1); atomicAdd(&ce[he[i]], 1); }
}

__global__ void k_invs(const int* __restrict__ cg, const int* __restrict__ cv,
                       const int* __restrict__ ce,
                       float* dinv, float* invv, float* inve){
  int i = blockIdx.x*256 + threadIdx.x;
  if (i < NN){
    float d = 1.0f + (float)cg[i];     // self-loop included
    dinv[i] = rsqrtf(d);
    invv[i] = 1.0f / fmaxf((float)cv[i], 1.0f);
  } else if (i < NP){
    dinv[i] = 0.f;                     // pad rows: keep GEMM rowscale finite
  }
  if (i < NEH) inve[i] = 1.0f / fmaxf((float)ce[i], 1.0f);
}

// exclusive scan, 256 elems/block (Hillis-Steele in LDS)
__global__ void k_scan1(const int* __restrict__ in, int* __restrict__ out,
                        int* __restrict__ bsum, int n){
  __shared__ int s[256];
  int t = threadIdx.x, i = blockIdx.x*256 + t;
  int v = (i < n) ? in[i] : 0;
  s[t] = v; __syncthreads();
  #pragma unroll
  for (int off = 1; off < 256; off <<= 1){
    int add = (t >= off) ? s[t-off] : 0;
    __syncthreads();
    s[t] += add;
    __syncthreads();
  }
  if (i < n) out[i] = s[t] - v;        // exclusive
  if (t == 255) bsum[blockIdx.x] = s[255];
}

__global__ void k_scan2(int* bsum, int nb){   // single block, nb <= 256
  __shared__ int s[256];
  int t = threadIdx.x;
  int v = (t < nb) ? bsum[t] : 0;
  s[t] = v; __syncthreads();
  #pragma unroll
  for (int off = 1; off < 256; off <<= 1){
    int add = (t >= off) ? s[t-off] : 0;
    __syncthreads();
    s[t] += add;
    __syncthreads();
  }
  if (t < nb) bsum[t] = s[t] - v;
}

__global__ void k_scan3(int* __restrict__ rp, int* __restrict__ cur,
                        const int* __restrict__ bsum, int n){
  int i = blockIdx.x*256 + threadIdx.x;
  if (i < n){ int v = rp[i] + bsum[blockIdx.x]; rp[i] = v; cur[i] = v; }
}

__global__ void k_fill_gcn(const int* __restrict__ src, const int* __restrict__ dst,
                           int* cur, int* __restrict__ csr){
  int i = blockIdx.x*256 + threadIdx.x;
  if (i < EE){ int p = atomicAdd(&cur[dst[i]], 1); csr[p] = src[i]; }
}

__global__ void k_fill_hg(const int* __restrict__ hv, const int* __restrict__ he,
                          int* cur_e, int* __restrict__ csr_e,
                          int* cur_v, int* __restrict__ csr_v){
  int i = blockIdx.x*256 + threadIdx.x;
  if (i < NINC){
    int v = hv[i], e = he[i];
    csr_e[atomicAdd(&cur_e[e], 1)] = v;
    csr_v[atomicAdd(&cur_v[v], 1)] = e;
  }
}

// ---------------- MFMA GEMM: C[NP][NCOL] = A[NP][KDIM] @ Wt[NCOL][KDIM]^T ----------------
// Optional rowscale (dinv) folded into the epilogue for GCN layers.
template<int KDIM, int NCOL>
__global__ __launch_bounds__(256) void k_gemm_mfma(
    const u16* __restrict__ A, const u16* __restrict__ Wt,
    const float* __restrict__ bias, const float* __restrict__ rowscale,
    u16* __restrict__ C, int relu)
{
  constexpr int NT  = NCOL/16;      // col tiles per wave (8 or 4)
  constexpr int LDA = 40;           // lds row stride (bf16): 2-way max conflict
  __shared__ __align__(16) u16 Asl[64][LDA];
  __shared__ __align__(16) u16 Wsl[NCOL][LDA];
  const int tid  = threadIdx.x;
  const int wave = tid >> 6, lane = tid & 63;
  const int l15 = lane & 15, l4 = lane >> 4;
  const int row0 = blockIdx.x * 64;
  const int ar = tid >> 2, aq = tid & 3;
  constexpr int NW = NCOL*4/256;

  f32x4 acc[NT] = {};

  for (int kk = 0; kk < KDIM; kk += 32){
    {
      uint4 v = *(const uint4*)(A + (size_t)(row0 + ar)*KDIM + kk + aq*8);
      *(uint4*)&Asl[ar][aq*8] = v;
    }
    #pragma unroll
    for (int w2 = 0; w2 < NW; ++w2){
      int c = tid + w2*256;
      int n = c >> 2, q = c & 3;
      uint4 v = *(const uint4*)(Wt + (size_t)n*KDIM + kk + q*8);
      *(uint4*)&Wsl[n][q*8] = v;
    }
    __syncthreads();
    short8 af = *(const short8*)&Asl[wave*16 + l15][l4*8];
    #pragma unroll
    for (int t = 0; t < NT; ++t){
      short8 bf = *(const short8*)&Wsl[t*16 + l15][l4*8];
      acc[t] = __builtin_amdgcn_mfma_f32_16x16x32_bf16(af, bf, acc[t], 0, 0, 0);
    }
    __syncthreads();
  }

  #pragma unroll
  for (int t = 0; t < NT; ++t){
    int gcol = t*16 + l15;
    float b = bias ? bias[gcol] : 0.f;
    #pragma unroll
    for (int e = 0; e < 4; ++e){
      int grow = row0 + wave*16 + l4*4 + e;
      float v = acc[t][e] + b;
      if (relu) v = fmaxf(v, 0.f);
      if (rowscale) v *= rowscale[grow];
      C[(size_t)grow*NCOL + gcol] = f2bu(v);
    }
  }
}

// ---------------- unified gather: one wave per dst row, 4 rows/block ----------------
// GCN: out = scale[d]*(self + sum_s h'[s]) + bias, h' pre-scaled by dinv.
// HG:  out = scale[d]*sum_s h[s] (+relu).
// F=128: u32 loads (2 bf16/lane); F=64: u16 loads.
template<int F, bool OUTBF, bool SELF>
__global__ __launch_bounds__(256) void k_gather(
    const int* __restrict__ rp, const int* __restrict__ cnt,
    const int* __restrict__ csr, const float* __restrict__ scale,
    const u16* __restrict__ h, const float* __restrict__ bias,
    void* __restrict__ out, int relu)
{
  const int wave = threadIdx.x >> 6, lane = threadIdx.x & 63;
  const int d = blockIdx.x*4 + wave;
  const int k0 = rp[d], n = cnt[d];

  if constexpr (F == 128){
    const uint* h32 = (const uint*)h;
    float a0=0,a1=0,b0=0,b1=0,c0=0,c1=0,e0=0,e1=0;
    if (SELF){
      uint v = h32[(size_t)d*64 + lane];
      a0 = us2f((u16)v); a1 = us2f((u16)(v>>16));
    }
    for (int base = 0; base < n; base += 64){
      int mm = n - base; if (mm > 64) mm = 64;
      int idx = (lane < mm) ? csr[k0 + base + lane] : 0;
      int jj = 0;
      for (; jj + 4 <= mm; jj += 4){
        int s0=__shfl(idx,jj), s1=__shfl(idx,jj+1), s2=__shfl(idx,jj+2), s3=__shfl(idx,jj+3);
        uint v0 = h32[(size_t)s0*64 + lane];
        uint v1 = h32[(size_t)s1*64 + lane];
        uint v2 = h32[(size_t)s2*64 + lane];
        uint v3 = h32[(size_t)s3*64 + lane];
        a0 += us2f((u16)v0); a1 += us2f((u16)(v0>>16));
        b0 += us2f((u16)v1); b1 += us2f((u16)(v1>>16));
        c0 += us2f((u16)v2); c1 += us2f((u16)(v2>>16));
        e0 += us2f((u16)v3); e1 += us2f((u16)(v3>>16));
      }
      for (; jj < mm; ++jj){
        int s = __shfl(idx, jj);
        uint v = h32[(size_t)s*64 + lane];
        a0 += us2f((u16)v); a1 += us2f((u16)(v>>16));
      }
    }
    float sc = scale[d];
    float o0 = ((a0+b0)+(c0+e0))*sc;
    float o1 = ((a1+b1)+(c1+e1))*sc;
    if (bias){ o0 += bias[lane*2]; o1 += bias[lane*2+1]; }
    if (relu){ o0 = fmaxf(o0,0.f); o1 = fmaxf(o1,0.f); }
    if (OUTBF){
      ((uint*)out)[(size_t)d*64 + lane] = (uint)f2bu(o0) | ((uint)f2bu(o1) << 16);
    } else {
      ((float2*)out)[(size_t)d*64 + lane] = make_float2(o0, o1);
    }
  } else { // F == 64
    float a=0,b=0,c=0,e=0;
    if (SELF) a = us2f(h[(size_t)d*64 + lane]);
    for (int base = 0; base < n; base += 64){
      int mm = n - base; if (mm > 64) mm = 64;
      int idx = (lane < mm) ? csr[k0 + base + lane] : 0;
      int jj = 0;
      for (; jj + 4 <= mm; jj += 4){
        int s0=__shfl(idx,jj), s1=__shfl(idx,jj+1), s2=__shfl(idx,jj+2), s3=__shfl(idx,jj+3);
        a += us2f(h[(size_t)s0*64 + lane]);
        b += us2f(h[(size_t)s1*64 + lane]);
        c += us2f(h[(size_t)s2*64 + lane]);
        e += us2f(h[(size_t)s3*64 + lane]);
      }
      for (; jj < mm; ++jj){
        int s = __shfl(idx, jj);
        a += us2f(h[(size_t)s*64 + lane]);
      }
    }
    float o = ((a+b)+(c+e))*scale[d];
    if (bias) o += bias[lane];
    if (relu) o = fmaxf(o, 0.f);
    if (OUTBF) ((u16*)out)[(size_t)d*64 + lane] = f2bu(o);
    else       ((float*)out)[(size_t)d*64 + lane] = o;
  }
}

// ---------------- embeds + row normalize ----------------
__global__ void k_embeds(const float* __restrict__ x2, const float* __restrict__ x4,
                         void* __restrict__ out, float* __restrict__ data,
                         const int* __restrict__ flag){
  int row  = blockIdx.x*4 + (threadIdx.x >> 6);
  int lane = threadIdx.x & 63;
  if (row >= NN) return;
  size_t idx = (size_t)row*64 + lane;
  float v = 0.5f*(x2[idx] + x4[idx]);
  float ss = v*v;
  #pragma unroll
  for (int off=32; off>0; off>>=1) ss += __shfl_xor(ss, off);
  float inv = rsqrtf(ss);
  data[idx] = v*inv;
  stf(out, EMB_OFF + idx, v, flag[0]);
}

// ---------------- clustering ----------------
__global__ void k_mu_init(const float* __restrict__ data, float* __restrict__ mu){
  int p = blockIdx.x*256 + threadIdx.x;
  if (p >= KCL*64) return;
  int k = p >> 6, f = p & 63;
  mu[p] = data[(size_t)k*(NN/KCL)*64 + f];   // init_idx = k*(N//K)
}

__global__ __launch_bounds__(128) void k_cluster_accum(const float* __restrict__ data,
    const float* __restrict__ mu, float* csum, float* cr, const int* nit, int iter)
{
  if (iter >= nit[0]) return;
  __shared__ float dt[128][65];
  __shared__ float rl[128][KCL];
  __shared__ float ms[KCL*64];
  int tid = threadIdx.x;
  int rowbase = blockIdx.x*128;
  for (int j=tid; j<KCL*64; j+=128) ms[j] = mu[j];
  for (int j=tid; j<128*64; j+=128){
    int rr = j>>6, f = j&63;
    int row = rowbase + rr;
    dt[rr][f] = (row<NN) ? data[(size_t)row*64+f] : 0.f;
  }
  __syncthreads();
  {
    int row = rowbase + tid;
    float dot[KCL];
    #pragma unroll
    for (int k2=0;k2<KCL;k2++) dot[k2]=0.f;
    for (int f=0; f<64; f++){
      float a = dt[tid][f];
      #pragma unroll
      for (int k2=0;k2<KCL;k2++) dot[k2] = fmaf(a, ms[k2*64+f], dot[k2]);
    }
    float m = -1e30f;
    #pragma unroll
    for (int k2=0;k2<KCL;k2++) m = fmaxf(m, 5.0f*dot[k2]);
    float s = 0.f, ev[KCL];
    #pragma unroll
    for (int k2=0;k2<KCL;k2++){ ev[k2] = expf(5.0f*dot[k2]-m); s += ev[k2]; }
    float inv = 1.0f/s;
    #pragma unroll
    for (int k2=0;k2<KCL;k2++) rl[tid][k2] = (row<NN) ? ev[k2]*inv : 0.f;
  }
  __syncthreads();
  for (int p=tid; p<KCL*64; p+=128){
    int k2 = p>>6, f = p&63;
    float acc = 0.f;
    for (int r2=0;r2<128;r2++) acc += rl[r2][k2]*dt[r2][f];
    unsafeAtomicAdd(&csum[p], acc);
  }
  if (tid < KCL){
    float acc = 0.f;
    for (int r2=0;r2<128;r2++) acc += rl[r2][tid];
    unsafeAtomicAdd(&cr[tid], acc);
  }
}

__global__ void k_mu_update(float* mu, float* csum, float* cr, const int* nit, int iter){
  if (iter >= nit[0]) return;
  int p = threadIdx.x;        // launched with exactly 640 threads
  float c = csum[p];
  float r = cr[p>>6];
  __syncthreads();
  mu[p] = c / r;
  csum[p] = 0.f;
  if (p < KCL) cr[p] = 0.f;
}

__global__ __launch_bounds__(128) void k_cluster_final(const float* __restrict__ data,
    const float* __restrict__ mu, void* __restrict__ out, const int* __restrict__ flag)
{
  __shared__ float dt[128][65];
  __shared__ float ms[KCL*64];
  int tid = threadIdx.x;
  int rowbase = blockIdx.x*128;
  for (int j=tid; j<KCL*64; j+=128) ms[j] = mu[j];
  for (int j=tid; j<128*64; j+=128){
    int rr = j>>6, f = j&63;
    int row = rowbase + rr;
    dt[rr][f] = (row<NN) ? data[(size_t)row*64+f] : 0.f;
  }
  __syncthreads();
  int row = rowbase + tid;
  if (row >= NN) return;
  int isbf = flag[0];
  float dot[KCL];
  #pragma unroll
  for (int k2=0;k2<KCL;k2++) dot[k2]=0.f;
  for (int f=0; f<64; f++){
    float a = dt[tid][f];
    #pragma unroll
    for (int k2=0;k2<KCL;k2++) dot[k2] = fmaf(a, ms[k2*64+f], dot[k2]);
  }
  float m = -1e30f;
  #pragma unroll
  for (int k2=0;k2<KCL;k2++) m = fmaxf(m, 5.0f*dot[k2]);
  float s = 0.f, ev[KCL];
  #pragma unroll
  for (int k2=0;k2<KCL;k2++){ ev[k2] = expf(5.0f*dot[k2]-m); s += ev[k2]; }
  float inv = 1.0f/s;
  #pragma unroll
  for (int k2=0;k2<KCL;k2++){
    stf(out, (size_t)D_OFF + (size_t)row*KCL + k2, dot[k2],     isbf);
    stf(out, (size_t)R_OFF + (size_t)row*KCL + k2, ev[k2]*inv,  isbf);
  }
}

__global__ void k_mu_out(const float* __restrict__ mu, void* __restrict__ out,
                         const int* __restrict__ flag){
  int p = blockIdx.x*256 + threadIdx.x;
  if (p < KCL*64) stf(out, MU_OFF + p, mu[p], flag[0]);
}

// ---------------- launch ----------------
extern "C" void kernel_launch(void* const* d_in, const int* in_sizes, int n_in,
                              void* d_out, int out_size, void* d_ws, size_t ws_size,
                              hipStream_t stream)
{
  const void* x   = d_in[0];
  const int*  ei  = (const int*)d_in[1];
  const int*  hv  = (const int*)d_in[2];
  const int*  he  = (const int*)d_in[3];
  const void* gW1 = d_in[4];
  const void* gb1 = d_in[5];
  const void* gW2 = d_in[6];
  const void* gb2 = d_in[7];
  const void* hW1 = d_in[8];
  const void* hb1 = d_in[9];
  const void* hW2 = d_in[10];
  const void* hb2 = d_in[11];
  const int*  nit = (const int*)d_in[12];

  float* ws = (float*)d_ws;
  size_t o = 0;
  u16*   xb  = (u16*)(ws + o); o += (size_t)NP*128;   // x bf16 NP x 256
  u16*   BAb = (u16*)(ws + o); o += (size_t)NP*64;    // GEMM out bf16 NP x 128
  u16*   BBb = (u16*)(ws + o); o += (size_t)NP*64;    // x1 bf16; later dataf f32
  u16*   BCb = (u16*)(ws + o); o += (size_t)NP*64;    // x3 bf16
  u16*   BDb = (u16*)(ws + o); o += (size_t)NEH*64;   // e_feat bf16 NEH x 128
  u16*  gW1t = (u16*)(ws + o); o += 16384;
  u16*  hW1t = (u16*)(ws + o); o += 16384;
  u16*  gW2t = (u16*)(ws + o); o += 4096;
  u16*  hW2t = (u16*)(ws + o); o += 4096;
  float* gb1f = ws + o; o += 128;
  float* hb1f = ws + o; o += 128;
  float* gb2f = ws + o; o += 64;
  float* hb2f = ws + o; o += 64;
  float* dinv = ws + o; o += 50048;
  float* invv = ws + o; o += 50048;
  float* inve = ws + o; o += 10048;
  float* mu   = ws + o; o += 640;
  float* csum = ws + o; o += 640;
  float* cr   = ws + o; o += 64;
  int*   dflg = (int*)(ws + o); o += 16;
  float* x2f   = (float*)xb;                 // aliases (xb dead by then)
  float* x4f   = (float*)xb + (size_t)NP*64;
  float* dataf = (float*)BBb;                // alias (BBb dead by then)
  // int region (CSR)
  int* ib = (int*)(ws + o);
  size_t io = 0;
  int* cg    = ib + io; io += NN;
  int* cv    = ib + io; io += NN;
  int* ce    = ib + io; io += NEH + 48;
  size_t cnt_ints = io;
  int* rp_g  = ib + io; io += NN;
  int* rp_v  = ib + io; io += NN;
  int* rp_e  = ib + io; io += NEH + 48;
  int* cu_g  = ib + io; io += NN;
  int* cu_v  = ib + io; io += NN;
  int* cu_e  = ib + io; io += NEH + 48;
  int* csr_g = ib + io; io += EE;
  int* csr_e = ib + io; io += NINC;
  int* csr_v = ib + io; io += NINC;
  int* bs_g  = ib + io; io += 256;
  int* bs_v  = ib + io; io += 256;
  int* bs_e  = ib + io; io += 256;

  const int* srcp = ei;
  const int* dstp = ei + EE;
  dim3 B(256);
  const int NBN = (NN + 255)/256;       // 196
  const int NBP = (NP + 255)/256;
  const int NBE = (NEH + 255)/256;      // 40

  // dtype detection + input prep
  k_detect<<<dim3(1), B, 0, stream>>>((const u16*)x, dflg);
  k_aconv<<<dim3(12500), B, 0, stream>>>(x, xb, dflg);
  k_wprep<<<dim3(128), B, 0, stream>>>(gW1, hW1, gW2, hW2, gb1, hb1, gb2, hb2,
                                       gW1t, hW1t, gW2t, hW2t,
                                       gb1f, hb1f, gb2f, hb2f, dflg);

  // ---- CSR build ----
  hipMemsetAsync(cg, 0, cnt_ints*sizeof(int), stream);
  k_cnt <<<dim3((EE+255)/256), B, 0, stream>>>(dstp, hv, he, cg, cv, ce);
  k_invs<<<dim3(NBP), B, 0, stream>>>(cg, cv, ce, dinv, invv, inve);
  k_scan1<<<dim3(NBN), B, 0, stream>>>(cg, rp_g, bs_g, NN);
  k_scan2<<<dim3(1),   B, 0, stream>>>(bs_g, NBN);
  k_scan3<<<dim3(NBN), B, 0, stream>>>(rp_g, cu_g, bs_g, NN);
  k_scan1<<<dim3(NBN), B, 0, stream>>>(cv, rp_v, bs_v, NN);
  k_scan2<<<dim3(1),   B, 0, stream>>>(bs_v, NBN);
  k_scan3<<<dim3(NBN), B, 0, stream>>>(rp_v, cu_v, bs_v, NN);
  k_scan1<<<dim3(NBE), B, 0, stream>>>(ce, rp_e, bs_e, NEH);
  k_scan2<<<dim3(1),   B, 0, stream>>>(bs_e, NBE);
  k_scan3<<<dim3(NBE), B, 0, stream>>>(rp_e, cu_e, bs_e, NEH);
  k_fill_gcn<<<dim3((EE+255)/256),   B, 0, stream>>>(srcp, dstp, cu_g, csr_g);
  k_fill_hg <<<dim3((NINC+255)/256), B, 0, stream>>>(hv, he, cu_e, csr_e, cu_v, csr_v);

  const int NB = NP/64;                 // 782 MFMA blocks
  // ---- GCN layer 1: BAb = (x@gW1)*dinv[row] ; x1 = gather+gb1, relu ----
  k_gemm_mfma<256,128><<<dim3(NB), B, 0, stream>>>(xb, gW1t, nullptr, dinv, BAb, 0);
  k_gather<128,true,true><<<dim3(NN/4), B, 0, stream>>>(rp_g, cg, csr_g, dinv,
                                                        BAb, gb1f, BBb, 1);
  // ---- HGNNP layer 1: BAb = x@hW1+hb1 ; ef ; x3 relu ----
  k_gemm_mfma<256,128><<<dim3(NB), B, 0, stream>>>(xb, hW1t, hb1f, nullptr, BAb, 0);
  k_gather<128,true,false><<<dim3(NEH/4), B, 0, stream>>>(rp_e, ce, csr_e, inve,
                                                          BAb, nullptr, BDb, 0);
  k_gather<128,true,false><<<dim3(NN/4), B, 0, stream>>>(rp_v, cv, csr_v, invv,
                                                         BDb, nullptr, BCb, 1);
  // ---- GCN layer 2 ----
  k_gemm_mfma<128,64><<<dim3(NB), B, 0, stream>>>(BBb, gW2t, nullptr, dinv, BAb, 0);
  k_gather<64,false,true><<<dim3(NN/4), B, 0, stream>>>(rp_g, cg, csr_g, dinv,
                                                        BAb, gb2f, x2f, 0);
  // ---- HGNNP layer 2 ----
  k_gemm_mfma<128,64><<<dim3(NB), B, 0, stream>>>(BCb, hW2t, hb2f, nullptr, BAb, 0);
  k_gather<64,true,false><<<dim3(NEH/4), B, 0, stream>>>(rp_e, ce, csr_e, inve,
                                                         BAb, nullptr, BDb, 0);
  k_gather<64,false,false><<<dim3(NN/4), B, 0, stream>>>(rp_v, cv, csr_v, invv,
                                                         BDb, nullptr, x4f, 0);

  // ---- embeds + normalized rows -> dataf ----
  k_embeds<<<dim3((NN+3)/4), B, 0, stream>>>(x2f, x4f, d_out, dataf, dflg);

  // ---- clustering ----
  k_mu_init<<<dim3(3), B, 0, stream>>>(dataf, mu);
  hipMemsetAsync(csum, 0, (640+64)*4, stream);
  const int CB = (NN + 127)/128;
  for (int it = 0; it < 4; ++it){   // gated by iter < *num_iter (setup: 1)
    k_cluster_accum<<<dim3(CB), dim3(128), 0, stream>>>(dataf, mu, csum, cr, nit, it);
    k_mu_update    <<<dim3(1),  dim3(640), 0, stream>>>(mu, csum, cr, nit, it);
  }
  k_cluster_final<<<dim3(CB), dim3(128), 0, stream>>>(dataf, mu, d_out, dflg);
  k_mu_out       <<<dim3(3),  B, 0, stream>>>(mu, d_out, dflg);
}

// Round 10
// 389.986 us; speedup vs baseline: 1.6791x; 1.0944x over previous
//
#include <hip/hip_runtime.h>
#include <hip/hip_bf16.h>

// HGNNP_GCN + ClusterNet forward, MI355X (round 10).
// R9 counters: k_cnt 51us + k_fill_gcn 53us, VALUBusy 0.4%, WRITE_SIZE 37-52MB
// -> CSR build is global-atomic (HBM RMW) bound. This round: atomic-free
// counting sort. Per-block LDS histograms (2x u16 packed per u32), private
// global writeout, per-bin chunk-prefix scan, then fill with LDS cursors
// (LDS atomicAdd returns packed local rank). Zero global atomics remain.

#define NN   50000   // nodes (= 12500*4)
#define NP   50048   // padded rows (782 * 64)
#define EE   800000  // directed edges (= 64*12500)
#define NINC 200000  // incidence entries (= 64*3125)
#define NEH  10000   // hyperedges
#define KCL  10      // clusters

// output element offsets (flat concat: mu | r | embeds | dist)
#define MU_OFF  0
#define R_OFF   640
#define EMB_OFF 500640
#define D_OFF   3700640

typedef __hip_bfloat16 bf16;
typedef unsigned short u16;
typedef unsigned int   u32;
typedef __attribute__((ext_vector_type(8))) short short8;
typedef __attribute__((ext_vector_type(4))) float f32x4;

__device__ __forceinline__ float b2f(bf16 v){ return __bfloat162float(v); }
__device__ __forceinline__ float us2f(u16 u){ return __uint_as_float(((unsigned)u) << 16); }
__device__ __forceinline__ u16 f2bu(float f){
  unsigned u = __float_as_uint(f);
  return (u16)((u + 0x7fffu + ((u >> 16) & 1u)) >> 16);   // RNE
}
__device__ __forceinline__ bf16 f2b(float f){
  u16 r = f2bu(f);
  bf16 h;
  reinterpret_cast<u16&>(h) = r;
  return h;
}
__device__ __forceinline__ float ldf(const void* p, size_t i, int isbf){
  return isbf ? b2f(((const bf16*)p)[i]) : ((const float*)p)[i];
}
__device__ __forceinline__ void stf(void* p, size_t i, float v, int isbf){
  if (isbf) ((bf16*)p)[i] = f2b(v);
  else      ((float*)p)[i] = v;
}

// ---------------- dtype detector ----------------
__global__ void k_detect(const u16* __restrict__ xr, int* flag){
  __shared__ int bad;
  if (threadIdx.x == 0) bad = 0;
  __syncthreads();
  for (int i = threadIdx.x; i < 4096; i += 256){
    int e = (xr[i] >> 7) & 0xFF;
    if (e >= 0xEF) bad = 1;     // f32 low-halves have random exponents
  }
  __syncthreads();
  if (threadIdx.x == 0) *flag = bad ? 0 : 1;   // 1 = bf16, 0 = f32
}

// ---------------- input prep ----------------
__global__ void k_aconv(const void* __restrict__ x, u16* __restrict__ xb,
                        const int* __restrict__ flag){
  int i = blockIdx.x*256 + threadIdx.x;      // one ushort4 (4 elems)
  const int n4 = NN*256/4;
  if (i >= n4) return;
  ushort4 o;
  if (flag[0]){
    o = ((const ushort4*)x)[i];
  } else {
    float4 v = ((const float4*)x)[i];
    o = make_ushort4(f2bu(v.x), f2bu(v.y), f2bu(v.z), f2bu(v.w));
  }
  ((ushort4*)xb)[i] = o;
}

__global__ void k_wprep(const void* gW1, const void* hW1, const void* gW2, const void* hW2,
                        const void* gb1, const void* hb1, const void* gb2, const void* hb2,
                        u16* gW1t, u16* hW1t, u16* gW2t, u16* hW2t,
                        float* gb1f, float* hb1f, float* gb2f, float* hb2f,
                        const int* __restrict__ flag){
  const int isbf = flag[0];
  int i = blockIdx.x*256 + threadIdx.x;
  if (i < 256*128){                    // Wt[n][k] = W[k][n], 128x256
    int n = i >> 8, k = i & 255;
    gW1t[i] = f2bu(ldf(gW1, (size_t)k*128 + n, isbf));
    hW1t[i] = f2bu(ldf(hW1, (size_t)k*128 + n, isbf));
  }
  if (i < 64*128){                     // 64x128
    int n = i >> 7, k = i & 127;
    gW2t[i] = f2bu(ldf(gW2, (size_t)k*64 + n, isbf));
    hW2t[i] = f2bu(ldf(hW2, (size_t)k*64 + n, isbf));
  }
  if (i < 128){ gb1f[i] = ldf(gb1,i,isbf); hb1f[i] = ldf(hb1,i,isbf); }
  if (i < 64) { gb2f[i] = ldf(gb2,i,isbf); hb2f[i] = ldf(hb2,i,isbf); }
}

// ---------------- atomic-free CSR build ----------------
// Bins packed 2 per u32 (lo: bin w, hi: bin w+WORDS); counts << 2^16 -> no carry.
// NCHUNK=64 chunks; NRANGE dst-ranges of 2*WORDS bins each.
template<int WORDS, int NRANGE, int NCHUNK>
__global__ __launch_bounds__(256) void k_hist(const int* __restrict__ key,
                                              u32* __restrict__ H, int chunk){
  __shared__ u32 hist[WORDS];
  int r = blockIdx.x / NCHUNK, c = blockIdx.x % NCHUNK;
  for (int i = threadIdx.x; i < WORDS; i += 256) hist[i] = 0;
  __syncthreads();
  int base = c*chunk, lo = r*2*WORDS;
  for (int i = threadIdx.x; i < chunk; i += 256){
    int d = key[base+i] - lo;
    if ((unsigned)d < (unsigned)(2*WORDS))
      atomicAdd(&hist[d < WORDS ? d : d-WORDS], d < WORDS ? 1u : 65536u);
  }
  __syncthreads();
  u32* out = H + (size_t)blockIdx.x*WORDS;     // layout [r][c][WORDS]
  for (int i = threadIdx.x; i < WORDS; i += 256) out[i] = hist[i];
}

// per-bin prefix over chunks (in place); emit total counts (unpacked)
template<int WORDS, int NRANGE, int NCHUNK>
__global__ void k_hscan(u32* __restrict__ H, int* __restrict__ cnt){
  int t = blockIdx.x*256 + threadIdx.x;
  if (t >= NRANGE*WORDS) return;
  int r = t / WORDS, w = t % WORDS;
  u32 run = 0;
  u32* col = H + (size_t)r*NCHUNK*WORDS + w;
  for (int b = 0; b < NCHUNK; ++b){
    u32 v = col[(size_t)b*WORDS];
    col[(size_t)b*WORDS] = run;       // prefix-before-chunk
    run += v;
  }
  cnt[r*2*WORDS + w]         = (int)(run & 0xffffu);
  cnt[r*2*WORDS + WORDS + w] = (int)(run >> 16);
}

// fill: LDS cursors start at this block's prefix; LDS atomicAdd returns rank
template<int WORDS, int NRANGE, int NCHUNK>
__global__ __launch_bounds__(256) void k_fill2(const int* __restrict__ key,
    const int* __restrict__ val, const u32* __restrict__ H,
    const int* __restrict__ rp, int* __restrict__ csr, int chunk){
  __shared__ u32 cur[WORDS];
  int r = blockIdx.x / NCHUNK, c = blockIdx.x % NCHUNK;
  const u32* pre = H + (size_t)blockIdx.x*WORDS;
  for (int i = threadIdx.x; i < WORDS; i += 256) cur[i] = pre[i];
  __syncthreads();
  int base = c*chunk, lo = r*2*WORDS;
  for (int i = threadIdx.x; i < chunk; i += 256){
    int dd = key[base+i];
    int d = dd - lo;
    if ((unsigned)d < (unsigned)(2*WORDS)){
      bool low = d < WORDS;
      u32 old = atomicAdd(&cur[low ? d : d-WORDS], low ? 1u : 65536u);
      u32 rank = low ? (old & 0xffffu) : (old >> 16);
      csr[rp[dd] + (int)rank] = val[base+i];
    }
  }
}

__global__ void k_invs(const int* __restrict__ cg, const int* __restrict__ cv,
                       const int* __restrict__ ce,
                       float* dinv, float* invv, float* inve){
  int i = blockIdx.x*256 + threadIdx.x;
  if (i < NN){
    float d = 1.0f + (float)cg[i];     // self-loop included
    dinv[i] = rsqrtf(d);
    invv[i] = 1.0f / fmaxf((float)cv[i], 1.0f);
  } else if (i < NP){
    dinv[i] = 0.f;                     // pad rows
  }
  if (i < NEH) inve[i] = 1.0f / fmaxf((float)ce[i], 1.0f);
}

// ---------------- fused row-pointer scans (3 structures in one launch) ----------------
// grid: 196 (cg->rp_g) + 196 (cv->rp_v) + 40 (ce->rp_e) = 432
__global__ void k_scan1_all(const int* cg, const int* cv, const int* ce,
                            int* rp_g, int* rp_v, int* rp_e,
                            int* bs_g, int* bs_v, int* bs_e){
  const int blk = blockIdx.x;
  const int* in; int* out; int* bsum; int n; int lb;
  if (blk < 196){ in=cg; out=rp_g; bsum=bs_g; n=NN; lb=blk; }
  else if (blk < 392){ in=cv; out=rp_v; bsum=bs_v; n=NN; lb=blk-196; }
  else { in=ce; out=rp_e; bsum=bs_e; n=NEH; lb=blk-392; }
  __shared__ int s[256];
  int t = threadIdx.x, i = lb*256 + t;
  int v = (i < n) ? in[i] : 0;
  s[t] = v; __syncthreads();
  #pragma unroll
  for (int off = 1; off < 256; off <<= 1){
    int add = (t >= off) ? s[t-off] : 0;
    __syncthreads();
    s[t] += add;
    __syncthreads();
  }
  if (i < n) out[i] = s[t] - v;        // exclusive
  if (t == 255) bsum[lb] = s[255];
}

__global__ void k_scan2_all(int* bs_g, int* bs_v, int* bs_e){
  int* bsum; int nb;
  if (blockIdx.x == 0){ bsum = bs_g; nb = 196; }
  else if (blockIdx.x == 1){ bsum = bs_v; nb = 196; }
  else { bsum = bs_e; nb = 40; }
  __shared__ int s[256];
  int t = threadIdx.x;
  int v = (t < nb) ? bsum[t] : 0;
  s[t] = v; __syncthreads();
  #pragma unroll
  for (int off = 1; off < 256; off <<= 1){
    int add = (t >= off) ? s[t-off] : 0;
    __syncthreads();
    s[t] += add;
    __syncthreads();
  }
  if (t < nb) bsum[t] = s[t] - v;
}

__global__ void k_scan3_all(int* rp_g, int* rp_v, int* rp_e,
                            const int* bs_g, const int* bs_v, const int* bs_e){
  const int blk = blockIdx.x;
  int* rp; const int* bsum; int n; int lb;
  if (blk < 196){ rp=rp_g; bsum=bs_g; n=NN; lb=blk; }
  else if (blk < 392){ rp=rp_v; bsum=bs_v; n=NN; lb=blk-196; }
  else { rp=rp_e; bsum=bs_e; n=NEH; lb=blk-392; }
  int i = lb*256 + threadIdx.x;
  if (i < n) rp[i] += bsum[lb];
}

// ---------------- MFMA GEMM ----------------
template<int KDIM, int NCOL>
__global__ __launch_bounds__(256) void k_gemm_mfma(
    const u16* __restrict__ A, const u16* __restrict__ Wt,
    const float* __restrict__ bias, const float* __restrict__ rowscale,
    u16* __restrict__ C, int relu)
{
  constexpr int NT  = NCOL/16;
  constexpr int LDA = 40;
  __shared__ __align__(16) u16 Asl[64][LDA];
  __shared__ __align__(16) u16 Wsl[NCOL][LDA];
  const int tid  = threadIdx.x;
  const int wave = tid >> 6, lane = tid & 63;
  const int l15 = lane & 15, l4 = lane >> 4;
  const int row0 = blockIdx.x * 64;
  const int ar = tid >> 2, aq = tid & 3;
  constexpr int NW = NCOL*4/256;

  f32x4 acc[NT] = {};

  for (int kk = 0; kk < KDIM; kk += 32){
    {
      uint4 v = *(const uint4*)(A + (size_t)(row0 + ar)*KDIM + kk + aq*8);
      *(uint4*)&Asl[ar][aq*8] = v;
    }
    #pragma unroll
    for (int w2 = 0; w2 < NW; ++w2){
      int c = tid + w2*256;
      int n = c >> 2, q = c & 3;
      uint4 v = *(const uint4*)(Wt + (size_t)n*KDIM + kk + q*8);
      *(uint4*)&Wsl[n][q*8] = v;
    }
    __syncthreads();
    short8 af = *(const short8*)&Asl[wave*16 + l15][l4*8];
    #pragma unroll
    for (int t = 0; t < NT; ++t){
      short8 bf = *(const short8*)&Wsl[t*16 + l15][l4*8];
      acc[t] = __builtin_amdgcn_mfma_f32_16x16x32_bf16(af, bf, acc[t], 0, 0, 0);
    }
    __syncthreads();
  }

  #pragma unroll
  for (int t = 0; t < NT; ++t){
    int gcol = t*16 + l15;
    float b = bias ? bias[gcol] : 0.f;
    #pragma unroll
    for (int e = 0; e < 4; ++e){
      int grow = row0 + wave*16 + l4*4 + e;
      float v = acc[t][e] + b;
      if (relu) v = fmaxf(v, 0.f);
      if (rowscale) v *= rowscale[grow];
      C[(size_t)grow*NCOL + gcol] = f2bu(v);
    }
  }
}

// ---------------- unified gather: one wave per dst row ----------------
template<int F, bool OUTBF, bool SELF>
__global__ __launch_bounds__(256) void k_gather(
    const int* __restrict__ rp, const int* __restrict__ cnt,
    const int* __restrict__ csr, const float* __restrict__ scale,
    const u16* __restrict__ h, const float* __restrict__ bias,
    void* __restrict__ out, int relu)
{
  const int wave = threadIdx.x >> 6, lane = threadIdx.x & 63;
  const int d = blockIdx.x*4 + wave;
  const int k0 = rp[d], n = cnt[d];

  if constexpr (F == 128){
    const uint* h32 = (const uint*)h;
    float a0=0,a1=0,b0=0,b1=0,c0=0,c1=0,e0=0,e1=0;
    if (SELF){
      uint v = h32[(size_t)d*64 + lane];
      a0 = us2f((u16)v); a1 = us2f((u16)(v>>16));
    }
    for (int base = 0; base < n; base += 64){
      int mm = n - base; if (mm > 64) mm = 64;
      int idx = (lane < mm) ? csr[k0 + base + lane] : 0;
      int jj = 0;
      for (; jj + 4 <= mm; jj += 4){
        int s0=__shfl(idx,jj), s1=__shfl(idx,jj+1), s2=__shfl(idx,jj+2), s3=__shfl(idx,jj+3);
        uint v0 = h32[(size_t)s0*64 + lane];
        uint v1 = h32[(size_t)s1*64 + lane];
        uint v2 = h32[(size_t)s2*64 + lane];
        uint v3 = h32[(size_t)s3*64 + lane];
        a0 += us2f((u16)v0); a1 += us2f((u16)(v0>>16));
        b0 += us2f((u16)v1); b1 += us2f((u16)(v1>>16));
        c0 += us2f((u16)v2); c1 += us2f((u16)(v2>>16));
        e0 += us2f((u16)v3); e1 += us2f((u16)(v3>>16));
      }
      for (; jj < mm; ++jj){
        int s = __shfl(idx, jj);
        uint v = h32[(size_t)s*64 + lane];
        a0 += us2f((u16)v); a1 += us2f((u16)(v>>16));
      }
    }
    float sc = scale[d];
    float o0 = ((a0+b0)+(c0+e0))*sc;
    float o1 = ((a1+b1)+(c1+e1))*sc;
    if (bias){ o0 += bias[lane*2]; o1 += bias[lane*2+1]; }
    if (relu){ o0 = fmaxf(o0,0.f); o1 = fmaxf(o1,0.f); }
    if (OUTBF){
      ((uint*)out)[(size_t)d*64 + lane] = (uint)f2bu(o0) | ((uint)f2bu(o1) << 16);
    } else {
      ((float2*)out)[(size_t)d*64 + lane] = make_float2(o0, o1);
    }
  } else { // F == 64
    float a=0,b=0,c=0,e=0;
    if (SELF) a = us2f(h[(size_t)d*64 + lane]);
    for (int base = 0; base < n; base += 64){
      int mm = n - base; if (mm > 64) mm = 64;
      int idx = (lane < mm) ? csr[k0 + base + lane] : 0;
      int jj = 0;
      for (; jj + 4 <= mm; jj += 4){
        int s0=__shfl(idx,jj), s1=__shfl(idx,jj+1), s2=__shfl(idx,jj+2), s3=__shfl(idx,jj+3);
        a += us2f(h[(size_t)s0*64 + lane]);
        b += us2f(h[(size_t)s1*64 + lane]);
        c += us2f(h[(size_t)s2*64 + lane]);
        e += us2f(h[(size_t)s3*64 + lane]);
      }
      for (; jj < mm; ++jj){
        int s = __shfl(idx, jj);
        a += us2f(h[(size_t)s*64 + lane]);
      }
    }
    float o = ((a+b)+(c+e))*scale[d];
    if (bias) o += bias[lane];
    if (relu) o = fmaxf(o, 0.f);
    if (OUTBF) ((u16*)out)[(size_t)d*64 + lane] = f2bu(o);
    else       ((float*)out)[(size_t)d*64 + lane] = o;
  }
}

// ---------------- embeds + row normalize ----------------
__global__ void k_embeds(const float* __restrict__ x2, const float* __restrict__ x4,
                         void* __restrict__ out, float* __restrict__ data,
                         const int* __restrict__ flag){
  int row  = blockIdx.x*4 + (threadIdx.x >> 6);
  int lane = threadIdx.x & 63;
  if (row >= NN) return;
  size_t idx = (size_t)row*64 + lane;
  float v = 0.5f*(x2[idx] + x4[idx]);
  float ss = v*v;
  #pragma unroll
  for (int off=32; off>0; off>>=1) ss += __shfl_xor(ss, off);
  float inv = rsqrtf(ss);
  data[idx] = v*inv;
  stf(out, EMB_OFF + idx, v, flag[0]);
}

// ---------------- clustering ----------------
__global__ void k_mu_init(const float* __restrict__ data, float* __restrict__ mu){
  int p = blockIdx.x*256 + threadIdx.x;
  if (p >= KCL*64) return;
  int k = p >> 6, f = p & 63;
  mu[p] = data[(size_t)k*(NN/KCL)*64 + f];   // init_idx = k*(N//K)
}

__global__ __launch_bounds__(128) void k_cluster_accum(const float* __restrict__ data,
    const float* __restrict__ mu, float* csum, float* cr, const int* nit, int iter)
{
  if (iter >= nit[0]) return;
  __shared__ float dt[128][65];
  __shared__ float rl[128][KCL];
  __shared__ float ms[KCL*64];
  int tid = threadIdx.x;
  int rowbase = blockIdx.x*128;
  for (int j=tid; j<KCL*64; j+=128) ms[j] = mu[j];
  for (int j=tid; j<128*64; j+=128){
    int rr = j>>6, f = j&63;
    int row = rowbase + rr;
    dt[rr][f] = (row<NN) ? data[(size_t)row*64+f] : 0.f;
  }
  __syncthreads();
  {
    int row = rowbase + tid;
    float dot[KCL];
    #pragma unroll
    for (int k2=0;k2<KCL;k2++) dot[k2]=0.f;
    for (int f=0; f<64; f++){
      float a = dt[tid][f];
      #pragma unroll
      for (int k2=0;k2<KCL;k2++) dot[k2] = fmaf(a, ms[k2*64+f], dot[k2]);
    }
    float m = -1e30f;
    #pragma unroll
    for (int k2=0;k2<KCL;k2++) m = fmaxf(m, 5.0f*dot[k2]);
    float s = 0.f, ev[KCL];
    #pragma unroll
    for (int k2=0;k2<KCL;k2++){ ev[k2] = expf(5.0f*dot[k2]-m); s += ev[k2]; }
    float inv = 1.0f/s;
    #pragma unroll
    for (int k2=0;k2<KCL;k2++) rl[tid][k2] = (row<NN) ? ev[k2]*inv : 0.f;
  }
  __syncthreads();
  for (int p=tid; p<KCL*64; p+=128){
    int k2 = p>>6, f = p&63;
    float acc = 0.f;
    for (int r2=0;r2<128;r2++) acc += rl[r2][k2]*dt[r2][f];
    unsafeAtomicAdd(&csum[p], acc);
  }
  if (tid < KCL){
    float acc = 0.f;
    for (int r2=0;r2<128;r2++) acc += rl[r2][tid];
    unsafeAtomicAdd(&cr[tid], acc);
  }
}

__global__ void k_mu_update(float* mu, float* csum, float* cr, const int* nit, int iter){
  if (iter >= nit[0]) return;
  int p = threadIdx.x;        // launched with exactly 640 threads
  float c = csum[p];
  float r = cr[p>>6];
  __syncthreads();
  mu[p] = c / r;
  csum[p] = 0.f;
  if (p < KCL) cr[p] = 0.f;
}

__global__ __launch_bounds__(128) void k_cluster_final(const float* __restrict__ data,
    const float* __restrict__ mu, void* __restrict__ out, const int* __restrict__ flag)
{
  __shared__ float dt[128][65];
  __shared__ float ms[KCL*64];
  int tid = threadIdx.x;
  int rowbase = blockIdx.x*128;
  for (int j=tid; j<KCL*64; j+=128) ms[j] = mu[j];
  for (int j=tid; j<128*64; j+=128){
    int rr = j>>6, f = j&63;
    int row = rowbase + rr;
    dt[rr][f] = (row<NN) ? data[(size_t)row*64+f] : 0.f;
  }
  __syncthreads();
  int row = rowbase + tid;
  if (row >= NN) return;
  int isbf = flag[0];
  float dot[KCL];
  #pragma unroll
  for (int k2=0;k2<KCL;k2++) dot[k2]=0.f;
  for (int f=0; f<64; f++){
    float a = dt[tid][f];
    #pragma unroll
    for (int k2=0;k2<KCL;k2++) dot[k2] = fmaf(a, ms[k2*64+f], dot[k2]);
  }
  float m = -1e30f;
  #pragma unroll
  for (int k2=0;k2<KCL;k2++) m = fmaxf(m, 5.0f*dot[k2]);
  float s = 0.f, ev[KCL];
  #pragma unroll
  for (int k2=0;k2<KCL;k2++){ ev[k2] = expf(5.0f*dot[k2]-m); s += ev[k2]; }
  float inv = 1.0f/s;
  #pragma unroll
  for (int k2=0;k2<KCL;k2++){
    stf(out, (size_t)D_OFF + (size_t)row*KCL + k2, dot[k2],     isbf);
    stf(out, (size_t)R_OFF + (size_t)row*KCL + k2, ev[k2]*inv,  isbf);
  }
}

__global__ void k_mu_out(const float* __restrict__ mu, void* __restrict__ out,
                         const int* __restrict__ flag){
  int p = blockIdx.x*256 + threadIdx.x;
  if (p < KCL*64) stf(out, MU_OFF + p, mu[p], flag[0]);
}

// ---------------- launch ----------------
extern "C" void kernel_launch(void* const* d_in, const int* in_sizes, int n_in,
                              void* d_out, int out_size, void* d_ws, size_t ws_size,
                              hipStream_t stream)
{
  const void* x   = d_in[0];
  const int*  ei  = (const int*)d_in[1];
  const int*  hv  = (const int*)d_in[2];
  const int*  he  = (const int*)d_in[3];
  const void* gW1 = d_in[4];
  const void* gb1 = d_in[5];
  const void* gW2 = d_in[6];
  const void* gb2 = d_in[7];
  const void* hW1 = d_in[8];
  const void* hb1 = d_in[9];
  const void* hW2 = d_in[10];
  const void* hb2 = d_in[11];
  const int*  nit = (const int*)d_in[12];

  float* ws = (float*)d_ws;
  size_t o = 0;
  u16*   xb  = (u16*)(ws + o); o += (size_t)NP*128;   // x bf16 NP x 256
  u16*   BAb = (u16*)(ws + o); o += (size_t)NP*64;    // GEMM out bf16 NP x 128
  u16*   BBb = (u16*)(ws + o); o += (size_t)NP*64;    // x1 bf16; later dataf f32
  u16*   BCb = (u16*)(ws + o); o += (size_t)NP*64;    // x3 bf16
  u16*   BDb = (u16*)(ws + o); o += (size_t)NEH*64;   // e_feat bf16 NEH x 128
  u16*  gW1t = (u16*)(ws + o); o += 16384;
  u16*  hW1t = (u16*)(ws + o); o += 16384;
  u16*  gW2t = (u16*)(ws + o); o += 4096;
  u16*  hW2t = (u16*)(ws + o); o += 4096;
  float* gb1f = ws + o; o += 128;
  float* hb1f = ws + o; o += 128;
  float* gb2f = ws + o; o += 64;
  float* hb2f = ws + o; o += 64;
  float* dinv = ws + o; o += 50048;
  float* invv = ws + o; o += 50048;
  float* inve = ws + o; o += 10048;
  float* mu   = ws + o; o += 640;
  float* csum = ws + o; o += 640;
  float* cr   = ws + o; o += 64;
  int*   dflg = (int*)(ws + o); o += 16;
  float* x2f   = (float*)xb;                 // aliases (xb dead by then)
  float* x4f   = (float*)xb + (size_t)NP*64;
  float* dataf = (float*)BBb;                // alias (BBb dead by then)
  // int region (CSR)
  int* ib = (int*)(ws + o);
  size_t io = 0;
  int* cg    = ib + io; io += NN;
  int* cv    = ib + io; io += NN;
  int* ce    = ib + io; io += NEH + 48;
  int* rp_g  = ib + io; io += NN;
  int* rp_v  = ib + io; io += NN;
  int* rp_e  = ib + io; io += NEH + 48;
  int* csr_g = ib + io; io += EE;
  int* csr_e = ib + io; io += NINC;
  int* csr_v = ib + io; io += NINC;
  int* bs_g  = ib + io; io += 256;
  int* bs_v  = ib + io; io += 256;
  int* bs_e  = ib + io; io += 256;
  u32* Hg = (u32*)(ib + io); io += 2*64*12500;   // 6.4MB
  u32* Hv = (u32*)(ib + io); io += 2*64*12500;   // 6.4MB
  u32* He = (u32*)(ib + io); io += 64*5000;      // 1.28MB

  const int* srcp = ei;
  const int* dstp = ei + EE;
  dim3 B(256);
  const int NBP = (NP + 255)/256;

  // dtype detection + input prep
  k_detect<<<dim3(1), B, 0, stream>>>((const u16*)x, dflg);
  k_aconv<<<dim3(12500), B, 0, stream>>>(x, xb, dflg);
  k_wprep<<<dim3(128), B, 0, stream>>>(gW1, hW1, gW2, hW2, gb1, hb1, gb2, hb2,
                                       gW1t, hW1t, gW2t, hW2t,
                                       gb1f, hb1f, gb2f, hb2f, dflg);

  // ---- atomic-free CSR build ----
  k_hist<12500,2,64><<<dim3(128), B, 0, stream>>>(dstp, Hg, 12500);  // gcn by dst
  k_hist<12500,2,64><<<dim3(128), B, 0, stream>>>(hv,   Hv, 3125);   // hg by vertex
  k_hist< 5000,1,64><<<dim3( 64), B, 0, stream>>>(he,   He, 3125);   // hg by hyperedge
  k_hscan<12500,2,64><<<dim3(98), B, 0, stream>>>(Hg, cg);
  k_hscan<12500,2,64><<<dim3(98), B, 0, stream>>>(Hv, cv);
  k_hscan< 5000,1,64><<<dim3(20), B, 0, stream>>>(He, ce);
  k_invs<<<dim3(NBP), B, 0, stream>>>(cg, cv, ce, dinv, invv, inve);
  k_scan1_all<<<dim3(432), B, 0, stream>>>(cg, cv, ce, rp_g, rp_v, rp_e, bs_g, bs_v, bs_e);
  k_scan2_all<<<dim3(3),   B, 0, stream>>>(bs_g, bs_v, bs_e);
  k_scan3_all<<<dim3(432), B, 0, stream>>>(rp_g, rp_v, rp_e, bs_g, bs_v, bs_e);
  k_fill2<12500,2,64><<<dim3(128), B, 0, stream>>>(dstp, srcp, Hg, rp_g, csr_g, 12500);
  k_fill2<12500,2,64><<<dim3(128), B, 0, stream>>>(hv,   he,   Hv, rp_v, csr_v, 3125);
  k_fill2< 5000,1,64><<<dim3( 64), B, 0, stream>>>(he,   hv,   He, rp_e, csr_e, 3125);

  const int NB = NP/64;                 // 782 MFMA blocks
  // ---- GCN layer 1: BAb = (x@gW1)*dinv[row] ; x1 = gather+gb1, relu ----
  k_gemm_mfma<256,128><<<dim3(NB), B, 0, stream>>>(xb, gW1t, nullptr, dinv, BAb, 0);
  k_gather<128,true,true><<<dim3(NN/4), B, 0, stream>>>(rp_g, cg, csr_g, dinv,
                                                        BAb, gb1f, BBb, 1);
  // ---- HGNNP layer 1 ----
  k_gemm_mfma<256,128><<<dim3(NB), B, 0, stream>>>(xb, hW1t, hb1f, nullptr, BAb, 0);
  k_gather<128,true,false><<<dim3(NEH/4), B, 0, stream>>>(rp_e, ce, csr_e, inve,
                                                          BAb, nullptr, BDb, 0);
  k_gather<128,true,false><<<dim3(NN/4), B, 0, stream>>>(rp_v, cv, csr_v, invv,
                                                         BDb, nullptr, BCb, 1);
  // ---- GCN layer 2 ----
  k_gemm_mfma<128,64><<<dim3(NB), B, 0, stream>>>(BBb, gW2t, nullptr, dinv, BAb, 0);
  k_gather<64,false,true><<<dim3(NN/4), B, 0, stream>>>(rp_g, cg, csr_g, dinv,
                                                        BAb, gb2f, x2f, 0);
  // ---- HGNNP layer 2 ----
  k_gemm_mfma<128,64><<<dim3(NB), B, 0, stream>>>(BCb, hW2t, hb2f, nullptr, BAb, 0);
  k_gather<64,true,false><<<dim3(NEH/4), B, 0, stream>>>(rp_e, ce, csr_e, inve,
                                                         BAb, nullptr, BDb, 0);
  k_gather<64,false,false><<<dim3(NN/4), B, 0, stream>>>(rp_v, cv, csr_v, invv,
                                                         BDb, nullptr, x4f, 0);

  // ---- embeds + normalized rows -> dataf ----
  k_embeds<<<dim3((NN+3)/4), B, 0, stream>>>(x2f, x4f, d_out, dataf, dflg);

  // ---- clustering ----
  k_mu_init<<<dim3(3), B, 0, stream>>>(dataf, mu);
  hipMemsetAsync(csum, 0, (640+64)*4, stream);
  const int CB = (NN + 127)/128;
  for (int it = 0; it < 4; ++it){   // gated by iter < *num_iter (setup: 1)
    k_cluster_accum<<<dim3(CB), dim3(128), 0, stream>>>(dataf, mu, csum, cr, nit, it);
    k_mu_update    <<<dim3(1),  dim3(640), 0, stream>>>(mu, csum, cr, nit, it);
  }
  k_cluster_final<<<dim3(CB), dim3(128), 0, stream>>>(dataf, mu, d_out, dflg);
  k_mu_out       <<<dim3(3),  B, 0, stream>>>(mu, d_out, dflg);
}